// Round 2
// baseline (318.763 us; speedup 1.0000x reference)
//
#include <hip/hip_runtime.h>
#include <hip/hip_bf16.h>
#include <cstdint>

typedef __attribute__((ext_vector_type(8))) short short8;
typedef __attribute__((ext_vector_type(4))) float f32x4;
typedef __attribute__((ext_vector_type(4))) float float4v;

#define HD 1024
#define SEQ 2048

// fp32 -> bf16 (round-to-nearest-even), raw bits; inputs are finite.
__device__ __forceinline__ unsigned short f2bf(float f) {
  uint32_t u = __builtin_bit_cast(uint32_t, f);
  return (unsigned short)((u + 0x7FFFu + ((u >> 16) & 1u)) >> 16);
}
__device__ __forceinline__ float bf2f(unsigned short s) {
  return __builtin_bit_cast(float, (uint32_t)s << 16);
}

// ---------------- transpose + hi/lo bf16 decompose: 4 fp32 1024x1024 matrices ----------
// out layout: wt[(z*2+0)*1M + n*1024 + k] = hi(B_z[k][n]); (z*2+1) plane = lo.
__global__ __launch_bounds__(256) void transpose_decomp4(
    const float* __restrict__ w0, const float* __restrict__ w1,
    const float* __restrict__ w2, const float* __restrict__ w3,
    unsigned short* __restrict__ wt) {
  __shared__ float tile[32][33];
  int z = blockIdx.z;
  const float* in = (z == 0) ? w0 : (z == 1) ? w1 : (z == 2) ? w2 : w3;
  unsigned short* oh = wt + (size_t)(z * 2) * 1024 * 1024;
  unsigned short* ol = oh + (size_t)1024 * 1024;
  int tx = threadIdx.x, ty = threadIdx.y;   // block (32,8)
  int x  = blockIdx.x * 32 + tx;
  int y0 = blockIdx.y * 32;
  for (int i = ty; i < 32; i += 8)
    tile[i][tx] = in[(size_t)(y0 + i) * HD + x];
  __syncthreads();
  int x2 = y0 + tx;               // k index after transpose
  int y2 = blockIdx.x * 32;       // n index after transpose
  for (int i = ty; i < 32; i += 8) {
    float v = tile[tx][i];
    unsigned short h = f2bf(v);
    float r = v - bf2f(h);
    oh[(size_t)(y2 + i) * HD + x2] = h;
    ol[(size_t)(y2 + i) * HD + x2] = f2bf(r);
  }
}

// ---------------- C[M,1024] = A_f32[M,1024] @ Bt(hi+lo)^T + bias ----------------
// Bt_hi/Bt_lo: bf16, Bt[n][k]. 64x64 block tile, 4 waves, split-precision:
// acc += Ahi*Bhi + Alo*Bhi + Ahi*Blo  (lo*lo dropped, ~2^-18 rel).
// Verified layouts: A-frag A[m=lane&15][k=quad*8+j]; B-frag B[k=quad*8+j][n=lane&15];
// C/D: col=lane&15, row=quad*4+reg.
__global__ __launch_bounds__(256) void gemm_f32split(
    const float* __restrict__ A,
    const unsigned short* __restrict__ Bth, const unsigned short* __restrict__ Btl,
    const float* __restrict__ bias, float* __restrict__ C) {
  __shared__ __align__(16) unsigned short Ash[64][40];  // pitch 40 shorts = 80B
  __shared__ __align__(16) unsigned short Asl[64][40];
  __shared__ __align__(16) unsigned short Bsh[64][40];
  __shared__ __align__(16) unsigned short Bsl[64][40];
  const int K = HD, N = HD;
  int m0 = blockIdx.x * 64;
  int n0 = blockIdx.y * 64;
  int tid  = threadIdx.x;
  int lane = tid & 63;
  int w    = tid >> 6;
  int quad = lane >> 4;
  int l16  = lane & 15;
  int srow = tid >> 2;          // 0..63
  int scol = (tid & 3) * 8;     // 0,8,16,24

  f32x4 acc0 = {0.f, 0.f, 0.f, 0.f};
  f32x4 acc1 = acc0, acc2 = acc0, acc3 = acc0;

  const float* Ap = A + (size_t)(m0 + srow) * K + scol;
  const unsigned short* Bph = Bth + (size_t)(n0 + srow) * K + scol;
  const unsigned short* Bpl = Btl + (size_t)(n0 + srow) * K + scol;

  for (int k0 = 0; k0 < K; k0 += 32) {
    float4v a0 = *(const float4v*)(Ap + k0);
    float4v a1 = *(const float4v*)(Ap + k0 + 4);
    short8 bh = *(const short8*)(Bph + k0);
    short8 bl = *(const short8*)(Bpl + k0);
    short8 ah, al;
    float av[8] = {a0.x, a0.y, a0.z, a0.w, a1.x, a1.y, a1.z, a1.w};
#pragma unroll
    for (int i = 0; i < 8; ++i) {
      unsigned short h = f2bf(av[i]);
      ah[i] = (short)h;
      al[i] = (short)f2bf(av[i] - bf2f(h));
    }
    __syncthreads();
    *(short8*)&Ash[srow][scol] = ah;
    *(short8*)&Asl[srow][scol] = al;
    *(short8*)&Bsh[srow][scol] = bh;
    *(short8*)&Bsl[srow][scol] = bl;
    __syncthreads();
    short8 fah = *(const short8*)&Ash[w * 16 + l16][quad * 8];
    short8 fal = *(const short8*)&Asl[w * 16 + l16][quad * 8];
    short8 bh0 = *(const short8*)&Bsh[ 0 + l16][quad * 8];
    short8 bh1 = *(const short8*)&Bsh[16 + l16][quad * 8];
    short8 bh2 = *(const short8*)&Bsh[32 + l16][quad * 8];
    short8 bh3 = *(const short8*)&Bsh[48 + l16][quad * 8];
    short8 bl0 = *(const short8*)&Bsl[ 0 + l16][quad * 8];
    short8 bl1 = *(const short8*)&Bsl[16 + l16][quad * 8];
    short8 bl2 = *(const short8*)&Bsl[32 + l16][quad * 8];
    short8 bl3 = *(const short8*)&Bsl[48 + l16][quad * 8];
    acc0 = __builtin_amdgcn_mfma_f32_16x16x32_bf16(fah, bh0, acc0, 0, 0, 0);
    acc1 = __builtin_amdgcn_mfma_f32_16x16x32_bf16(fah, bh1, acc1, 0, 0, 0);
    acc2 = __builtin_amdgcn_mfma_f32_16x16x32_bf16(fah, bh2, acc2, 0, 0, 0);
    acc3 = __builtin_amdgcn_mfma_f32_16x16x32_bf16(fah, bh3, acc3, 0, 0, 0);
    acc0 = __builtin_amdgcn_mfma_f32_16x16x32_bf16(fal, bh0, acc0, 0, 0, 0);
    acc1 = __builtin_amdgcn_mfma_f32_16x16x32_bf16(fal, bh1, acc1, 0, 0, 0);
    acc2 = __builtin_amdgcn_mfma_f32_16x16x32_bf16(fal, bh2, acc2, 0, 0, 0);
    acc3 = __builtin_amdgcn_mfma_f32_16x16x32_bf16(fal, bh3, acc3, 0, 0, 0);
    acc0 = __builtin_amdgcn_mfma_f32_16x16x32_bf16(fah, bl0, acc0, 0, 0, 0);
    acc1 = __builtin_amdgcn_mfma_f32_16x16x32_bf16(fah, bl1, acc1, 0, 0, 0);
    acc2 = __builtin_amdgcn_mfma_f32_16x16x32_bf16(fah, bl2, acc2, 0, 0, 0);
    acc3 = __builtin_amdgcn_mfma_f32_16x16x32_bf16(fah, bl3, acc3, 0, 0, 0);
  }

  int r0 = m0 + w * 16 + quad * 4;
  f32x4 accs[4] = {acc0, acc1, acc2, acc3};
#pragma unroll
  for (int t = 0; t < 4; ++t) {
    int col = n0 + t * 16 + l16;
    float bv = bias[col];
#pragma unroll
    for (int i = 0; i < 4; ++i)
      C[(size_t)(r0 + i) * N + col] = accs[t][i] + bv;
  }
}

// ---------------- RoPE in place on q and k ([4096,1024] fp32 each) ----------------
// pair (d, d+512), angle theta = s * 10000^(-d/512), s = row % 2048
__global__ __launch_bounds__(256) void rope_k(float* __restrict__ q, float* __restrict__ k) {
  int idx = blockIdx.x * 256 + threadIdx.x;   // 0 .. 2*4096*512-1
  float* p = (idx >> 21) ? k : q;
  int r = (idx >> 9) & 4095;
  int d = idx & 511;
  int s = r & (SEQ - 1);
  float theta = (float)s * powf(10000.f, -(float)d * (1.0f / 512.0f));
  float sv, cv;
  sincosf(theta, &sv, &cv);
  size_t base = (size_t)r * HD;
  float x1 = p[base + d];
  float x2 = p[base + d + 512];
  p[base + d]       = x1 * cv - x2 * sv;
  p[base + d + 512] = x2 * cv + x1 * sv;
}

// ---------------- per-(b,s) head-attention (fp32) ----------------
// scores[h][t] = q[h,:].k[t,:]/8 ; softmax over t ; ctx[h][d] = sum_t attn*v[t][d]
// writes attn and ctx in the transpose(0,2,1,3).reshape scrambled layout.
__global__ __launch_bounds__(256) void attn_k(
    const float* __restrict__ q, const float* __restrict__ kk, const float* __restrict__ v,
    float* __restrict__ attn_out, float* __restrict__ ctx_r) {
  __shared__ float qs[16][68], ks[16][68], vs[16][68], as[16][17];
  int m = blockIdx.x;            // b*S + s
  int tid = threadIdx.x;
  size_t base = (size_t)m * HD;
  for (int j = tid; j < 1024; j += 256) {
    int h = j >> 6, d = j & 63;
    qs[h][d] = q[base + j];
    ks[h][d] = kk[base + j];
    vs[h][d] = v[base + j];
  }
  __syncthreads();
  int h = tid >> 4, t = tid & 15;
  float sc = 0.f;
#pragma unroll
  for (int d = 0; d < 64; ++d) sc = fmaf(qs[h][d], ks[t][d], sc);
  sc *= 0.125f;   // 1/sqrt(64)
  float mx = sc;
  mx = fmaxf(mx, __shfl_xor(mx, 1));
  mx = fmaxf(mx, __shfl_xor(mx, 2));
  mx = fmaxf(mx, __shfl_xor(mx, 4));
  mx = fmaxf(mx, __shfl_xor(mx, 8));
  float e = expf(sc - mx);
  float sum = e;
  sum += __shfl_xor(sum, 1);
  sum += __shfl_xor(sum, 2);
  sum += __shfl_xor(sum, 4);
  sum += __shfl_xor(sum, 8);
  float a = e / sum;
  attn_out[(size_t)m * 256 + tid] = a;
  as[h][t] = a;
  __syncthreads();
  int b = m >> 11, s = m & (SEQ - 1);
  for (int j = tid; j < 1024; j += 256) {
    int h2 = j >> 6, d = j & 63;
    float c = 0.f;
#pragma unroll
    for (int t2 = 0; t2 < 16; ++t2) c = fmaf(as[h2][t2], vs[t2][d], c);
    int row = b * SEQ + h2 * 128 + (s >> 4);
    int col = (s & 15) * 64 + d;
    ctx_r[(size_t)row * HD + col] = c;
  }
}

extern "C" void kernel_launch(void* const* d_in, const int* in_sizes, int n_in,
                              void* d_out, int out_size, void* d_ws, size_t ws_size,
                              hipStream_t stream) {
  const float* inputs  = (const float*)d_in[0];
  const float* context = (const float*)d_in[1];
  const float* Wq = (const float*)d_in[2];
  const float* bq = (const float*)d_in[3];
  const float* Wk = (const float*)d_in[4];
  const float* bk = (const float*)d_in[5];
  const float* Wv = (const float*)d_in[6];
  const float* bv = (const float*)d_in[7];
  const float* Wo = (const float*)d_in[8];
  const float* bo = (const float*)d_in[9];

  float* out  = (float*)d_out;                     // [2,2048,1024] flat
  float* attn = out + (size_t)4096 * 1024;         // [2,2048,16,16] flat

  float* q   = (float*)d_ws;                       // [4096,1024] fp32
  float* k   = q   + (size_t)4096 * 1024;
  float* v   = k   + (size_t)4096 * 1024;
  float* ctx = v   + (size_t)4096 * 1024;          // scrambled ctx
  unsigned short* wt = (unsigned short*)(ctx + (size_t)4096 * 1024);  // 8 planes of 1M bf16

  transpose_decomp4<<<dim3(32, 32, 4), dim3(32, 8), 0, stream>>>(Wq, Wk, Wv, Wo, wt);

  const size_t P = (size_t)1024 * 1024;
  gemm_f32split<<<dim3(64, 16), 256, 0, stream>>>(inputs,  wt + 0 * P, wt + 1 * P, bq, q);
  gemm_f32split<<<dim3(64, 16), 256, 0, stream>>>(context, wt + 2 * P, wt + 3 * P, bk, k);
  gemm_f32split<<<dim3(64, 16), 256, 0, stream>>>(context, wt + 4 * P, wt + 5 * P, bv, v);

  rope_k<<<16384, 256, 0, stream>>>(q, k);

  attn_k<<<4096, 256, 0, stream>>>(q, k, v, attn, ctx);

  gemm_f32split<<<dim3(64, 16), 256, 0, stream>>>(ctx, wt + 6 * P, wt + 7 * P, bo, out);
}

// Round 3
// 304.388 us; speedup vs baseline: 1.0472x; 1.0472x over previous
//
#include <hip/hip_runtime.h>
#include <hip/hip_bf16.h>
#include <cstdint>

typedef __attribute__((ext_vector_type(8))) short short8;
typedef __attribute__((ext_vector_type(4))) float f32x4;
typedef __attribute__((ext_vector_type(4))) float float4v;
typedef __attribute__((ext_vector_type(4))) unsigned short us4;

#define HD 1024
#define SEQ 2048

// fp32 -> bf16 (round-to-nearest-even), raw bits; inputs are finite.
__device__ __forceinline__ unsigned short f2bf(float f) {
  uint32_t u = __builtin_bit_cast(uint32_t, f);
  return (unsigned short)((u + 0x7FFFu + ((u >> 16) & 1u)) >> 16);
}
__device__ __forceinline__ float bf2f(unsigned short s) {
  return __builtin_bit_cast(float, (uint32_t)s << 16);
}

// async global->LDS, 16B per lane, dest = wave-uniform base + lane*16
__device__ __forceinline__ void gload16(const unsigned short* g, unsigned short* l) {
  __builtin_amdgcn_global_load_lds(
      (const __attribute__((address_space(1))) void*)g,
      (__attribute__((address_space(3))) void*)l, 16, 0, 0);
}

// ---------------- hi/lo decompose of inputs & context ----------------
__global__ __launch_bounds__(256) void decomp2(
    const float* __restrict__ X, const float* __restrict__ Y,
    unsigned short* __restrict__ Xh, unsigned short* __restrict__ Xl,
    unsigned short* __restrict__ Yh, unsigned short* __restrict__ Yl) {
  int i = blockIdx.x * 256 + threadIdx.x;     // over 1M float4s
  const float* src = blockIdx.y ? Y : X;
  unsigned short* oh = blockIdx.y ? Yh : Xh;
  unsigned short* ol = blockIdx.y ? Yl : Xl;
  float4v v = ((const float4v*)src)[i];
  us4 h, lo;
#pragma unroll
  for (int j = 0; j < 4; ++j) {
    unsigned short hh = f2bf(v[j]);
    h[j] = hh;
    lo[j] = f2bf(v[j] - bf2f(hh));
  }
  ((us4*)oh)[i] = h;
  ((us4*)ol)[i] = lo;
}

// ---------------- transpose + hi/lo decompose: 4 fp32 1024x1024 weights ----------
// wt[(z*2+0)*1M + n*1024 + k] = hi(W_z[k][n]); (z*2+1) plane = lo.
__global__ __launch_bounds__(256) void transpose_decomp4(
    const float* __restrict__ w0, const float* __restrict__ w1,
    const float* __restrict__ w2, const float* __restrict__ w3,
    unsigned short* __restrict__ wt) {
  __shared__ float tile[32][33];
  int z = blockIdx.z;
  const float* in = (z == 0) ? w0 : (z == 1) ? w1 : (z == 2) ? w2 : w3;
  unsigned short* oh = wt + (size_t)(z * 2) * 1024 * 1024;
  unsigned short* ol = oh + (size_t)1024 * 1024;
  int tx = threadIdx.x, ty = threadIdx.y;   // block (32,8)
  int x  = blockIdx.x * 32 + tx;
  int y0 = blockIdx.y * 32;
  for (int i = ty; i < 32; i += 8)
    tile[i][tx] = in[(size_t)(y0 + i) * HD + x];
  __syncthreads();
  int x2 = y0 + tx;               // k index after transpose
  int y2 = blockIdx.x * 32;       // n index after transpose
  for (int i = ty; i < 32; i += 8) {
    float v = tile[tx][i];
    unsigned short h = f2bf(v);
    oh[(size_t)(y2 + i) * HD + x2] = h;
    ol[(size_t)(y2 + i) * HD + x2] = f2bf(v - bf2f(h));
  }
}

// ---------------- C[M,1024] = (Ah+Al)[M,1024] @ (Bh+Bl)[1024,1024]^T + bias ------
// All operands bf16 planes, B pre-transposed (Bt[n][k]).
// 128x128 block tile, 512 threads = 8 waves (2 m x 4 n), wave = 64x32 (4x2 tiles).
// Split-precision: acc += Ah*Bh + Al*Bh + Ah*Bl.
// LDS: 4 planes [128][32] bf16, XOR-swizzled chunks: slot c of row r holds global
// k-chunk c ^ ((r>>1)&3)  -> frag ds_read_b128 is 2-way-per-phase (free).
// global_load_lds width 16: wave w stages rows w*16..w*16+15 of each plane.
__global__ __launch_bounds__(512) void gemm_split(
    const unsigned short* __restrict__ Ah, const unsigned short* __restrict__ Al,
    const unsigned short* __restrict__ Bth, const unsigned short* __restrict__ Btl,
    const float* __restrict__ bias, float* __restrict__ C) {
  __shared__ __align__(16) unsigned short lds[4][128][32];
  const int K = HD, N = HD;
  int m0 = blockIdx.x * 128;
  int n0 = blockIdx.y * 128;
  int tid = threadIdx.x;
  int lane = tid & 63;
  int w    = tid >> 6;            // 0..7
  int quad = lane >> 4;
  int l16  = lane & 15;
  int wm = (w >> 2) * 64;         // 0 / 64
  int wn = (w & 3) * 32;          // 0 / 32 / 64 / 96

  // ---- staging source offsets (one instr per plane per wave) ----
  int lr = lane >> 2;             // 0..15 (row within segment)
  int lc = lane & 3;              // chunk slot
  int r  = w * 16 + lr;           // row 0..127
  int g  = lc ^ ((r >> 1) & 3);   // global chunk fetched into slot lc
  const unsigned short* src[4];
  src[0] = Ah  + (size_t)(m0 + r) * K + g * 8;
  src[1] = Al  + (size_t)(m0 + r) * K + g * 8;
  src[2] = Bth + (size_t)(n0 + r) * K + g * 8;
  src[3] = Btl + (size_t)(n0 + r) * K + g * 8;
  unsigned short* dst[4];
#pragma unroll
  for (int p = 0; p < 4; ++p) dst[p] = &lds[p][w * 16][0];

  f32x4 acc[4][2];
#pragma unroll
  for (int t = 0; t < 4; ++t)
#pragma unroll
    for (int u = 0; u < 2; ++u) acc[t][u] = (f32x4){0.f, 0.f, 0.f, 0.f};

  int sl8 = (quad ^ ((l16 >> 1) & 3)) * 8;   // swizzled chunk offset (shorts)

  for (int k0 = 0; k0 < K; k0 += 32) {
    __syncthreads();              // previous iter's frag reads complete
#pragma unroll
    for (int p = 0; p < 4; ++p) gload16(src[p] + k0, dst[p]);
    __syncthreads();              // drains vmcnt -> staged data visible

    short8 ah[4], al[4], bh[2], bl[2];
#pragma unroll
    for (int t = 0; t < 4; ++t) {
      int rr = wm + t * 16 + l16;
      ah[t] = *(const short8*)&lds[0][rr][sl8];
      al[t] = *(const short8*)&lds[1][rr][sl8];
    }
#pragma unroll
    for (int u = 0; u < 2; ++u) {
      int rn = wn + u * 16 + l16;
      bh[u] = *(const short8*)&lds[2][rn][sl8];
      bl[u] = *(const short8*)&lds[3][rn][sl8];
    }
#pragma unroll
    for (int t = 0; t < 4; ++t)
#pragma unroll
      for (int u = 0; u < 2; ++u)
        acc[t][u] = __builtin_amdgcn_mfma_f32_16x16x32_bf16(ah[t], bh[u], acc[t][u], 0, 0, 0);
#pragma unroll
    for (int t = 0; t < 4; ++t)
#pragma unroll
      for (int u = 0; u < 2; ++u)
        acc[t][u] = __builtin_amdgcn_mfma_f32_16x16x32_bf16(al[t], bh[u], acc[t][u], 0, 0, 0);
#pragma unroll
    for (int t = 0; t < 4; ++t)
#pragma unroll
      for (int u = 0; u < 2; ++u)
        acc[t][u] = __builtin_amdgcn_mfma_f32_16x16x32_bf16(ah[t], bl[u], acc[t][u], 0, 0, 0);
  }

#pragma unroll
  for (int t = 0; t < 4; ++t) {
    int row = m0 + wm + t * 16 + quad * 4;
#pragma unroll
    for (int u = 0; u < 2; ++u) {
      int col = n0 + wn + u * 16 + l16;
      float bv = bias[col];
#pragma unroll
      for (int i = 0; i < 4; ++i)
        C[(size_t)(row + i) * N + col] = acc[t][u][i] + bv;
    }
  }
}

// ---------------- RoPE in place on q and k ([4096,1024] fp32 each) ----------------
__global__ __launch_bounds__(256) void rope_k(float* __restrict__ q, float* __restrict__ k) {
  int idx = blockIdx.x * 256 + threadIdx.x;   // 0 .. 2*4096*512-1
  float* p = (idx >> 21) ? k : q;
  int r = (idx >> 9) & 4095;
  int d = idx & 511;
  int s = r & (SEQ - 1);
  float theta = (float)s * powf(10000.f, -(float)d * (1.0f / 512.0f));
  float sv, cv;
  sincosf(theta, &sv, &cv);
  size_t base = (size_t)r * HD;
  float x1 = p[base + d];
  float x2 = p[base + d + 512];
  p[base + d]       = x1 * cv - x2 * sv;
  p[base + d + 512] = x2 * cv + x1 * sv;
}

// ---------------- per-(b,s) head-attention (fp32), ctx written as hi/lo bf16 -------
__global__ __launch_bounds__(256) void attn_k(
    const float* __restrict__ q, const float* __restrict__ kk, const float* __restrict__ v,
    float* __restrict__ attn_out,
    unsigned short* __restrict__ ctx_h, unsigned short* __restrict__ ctx_l) {
  __shared__ float qs[16][68], ks[16][68], vs[16][68], as[16][17];
  int m = blockIdx.x;            // b*S + s
  int tid = threadIdx.x;
  size_t base = (size_t)m * HD;
  for (int j = tid; j < 1024; j += 256) {
    int h = j >> 6, d = j & 63;
    qs[h][d] = q[base + j];
    ks[h][d] = kk[base + j];
    vs[h][d] = v[base + j];
  }
  __syncthreads();
  int h = tid >> 4, t = tid & 15;
  float sc = 0.f;
#pragma unroll
  for (int d = 0; d < 64; ++d) sc = fmaf(qs[h][d], ks[t][d], sc);
  sc *= 0.125f;   // 1/sqrt(64)
  float mx = sc;
  mx = fmaxf(mx, __shfl_xor(mx, 1));
  mx = fmaxf(mx, __shfl_xor(mx, 2));
  mx = fmaxf(mx, __shfl_xor(mx, 4));
  mx = fmaxf(mx, __shfl_xor(mx, 8));
  float e = expf(sc - mx);
  float sum = e;
  sum += __shfl_xor(sum, 1);
  sum += __shfl_xor(sum, 2);
  sum += __shfl_xor(sum, 4);
  sum += __shfl_xor(sum, 8);
  float a = e / sum;
  attn_out[(size_t)m * 256 + tid] = a;
  as[h][t] = a;
  __syncthreads();
  int b = m >> 11, s = m & (SEQ - 1);
  for (int j = tid; j < 1024; j += 256) {
    int h2 = j >> 6, d = j & 63;
    float c = 0.f;
#pragma unroll
    for (int t2 = 0; t2 < 16; ++t2) c = fmaf(as[h2][t2], vs[t2][d], c);
    int row = b * SEQ + h2 * 128 + (s >> 4);
    int col = (s & 15) * 64 + d;
    size_t off = (size_t)row * HD + col;
    unsigned short hh = f2bf(c);
    ctx_h[off] = hh;
    ctx_l[off] = f2bf(c - bf2f(hh));
  }
}

extern "C" void kernel_launch(void* const* d_in, const int* in_sizes, int n_in,
                              void* d_out, int out_size, void* d_ws, size_t ws_size,
                              hipStream_t stream) {
  const float* inputs  = (const float*)d_in[0];
  const float* context = (const float*)d_in[1];
  const float* Wq = (const float*)d_in[2];
  const float* bq = (const float*)d_in[3];
  const float* Wk = (const float*)d_in[4];
  const float* bk = (const float*)d_in[5];
  const float* Wv = (const float*)d_in[6];
  const float* bv = (const float*)d_in[7];
  const float* Wo = (const float*)d_in[8];
  const float* bo = (const float*)d_in[9];

  float* out  = (float*)d_out;                     // [2,2048,1024] flat
  float* attn = out + (size_t)4096 * 1024;         // [2,2048,16,16] flat

  // workspace layout (80 MB total, v / ctx planes alias dead regions):
  const size_t MB = 1ull << 20;
  char* wsb = (char*)d_ws;
  float* q = (float*)(wsb + 0 * MB);               // 16 MB
  float* k = (float*)(wsb + 16 * MB);              // 16 MB
  unsigned short* wt = (unsigned short*)(wsb + 32 * MB);   // 8 planes x 2 MB
  unsigned short* Ih = (unsigned short*)(wsb + 48 * MB);   // 8 MB
  unsigned short* Il = (unsigned short*)(wsb + 56 * MB);   // 8 MB
  unsigned short* Ch = (unsigned short*)(wsb + 64 * MB);   // 8 MB
  unsigned short* Cl = (unsigned short*)(wsb + 72 * MB);   // 8 MB
  float* v = (float*)(wsb + 48 * MB);              // aliases Ih/Il (dead after Q gemm)
  unsigned short* ctxh = Ch;                       // alias (dead after V gemm)
  unsigned short* ctxl = Cl;

  decomp2<<<dim3(4096, 2), 256, 0, stream>>>(inputs, context, Ih, Il, Ch, Cl);
  transpose_decomp4<<<dim3(32, 32, 4), dim3(32, 8), 0, stream>>>(Wq, Wk, Wv, Wo, wt);

  const size_t P = (size_t)1024 * 1024;
  gemm_split<<<dim3(32, 8), 512, 0, stream>>>(Ih, Il, wt + 0 * P, wt + 1 * P, bq, q);
  gemm_split<<<dim3(32, 8), 512, 0, stream>>>(Ch, Cl, wt + 2 * P, wt + 3 * P, bk, k);
  gemm_split<<<dim3(32, 8), 512, 0, stream>>>(Ch, Cl, wt + 4 * P, wt + 5 * P, bv, v);

  rope_k<<<16384, 256, 0, stream>>>(q, k);

  attn_k<<<4096, 256, 0, stream>>>(q, k, v, attn, ctxh, ctxl);

  gemm_split<<<dim3(32, 8), 512, 0, stream>>>(ctxh, ctxl, wt + 6 * P, wt + 7 * P, bo, out);
}

// Round 4
// 240.377 us; speedup vs baseline: 1.3261x; 1.2663x over previous
//
#include <hip/hip_runtime.h>
#include <hip/hip_bf16.h>
#include <cstdint>

typedef __attribute__((ext_vector_type(8))) short short8;
typedef __attribute__((ext_vector_type(4))) float f32x4;
typedef __attribute__((ext_vector_type(4))) float float4v;
typedef __attribute__((ext_vector_type(4))) unsigned short us4;

#define HD 1024
#define SEQ 2048

// fp32 -> bf16 (round-to-nearest-even), raw bits; inputs are finite.
__device__ __forceinline__ unsigned short f2bf(float f) {
  uint32_t u = __builtin_bit_cast(uint32_t, f);
  return (unsigned short)((u + 0x7FFFu + ((u >> 16) & 1u)) >> 16);
}
__device__ __forceinline__ float bf2f(unsigned short s) {
  return __builtin_bit_cast(float, (uint32_t)s << 16);
}

// async global->LDS, 16B per lane, dest = wave-uniform base + lane*16
__device__ __forceinline__ void gload16(const unsigned short* g, unsigned short* l) {
  __builtin_amdgcn_global_load_lds(
      (const __attribute__((address_space(1))) void*)g,
      (__attribute__((address_space(3))) void*)l, 16, 0, 0);
}

// ---------------- hi/lo decompose of inputs & context ----------------
__global__ __launch_bounds__(256) void decomp2(
    const float* __restrict__ X, const float* __restrict__ Y,
    unsigned short* __restrict__ Xh, unsigned short* __restrict__ Xl,
    unsigned short* __restrict__ Yh, unsigned short* __restrict__ Yl) {
  int i = blockIdx.x * 256 + threadIdx.x;     // over 1M float4s
  const float* src = blockIdx.y ? Y : X;
  unsigned short* oh = blockIdx.y ? Yh : Xh;
  unsigned short* ol = blockIdx.y ? Yl : Xl;
  float4v v = ((const float4v*)src)[i];
  us4 h, lo;
#pragma unroll
  for (int j = 0; j < 4; ++j) {
    unsigned short hh = f2bf(v[j]);
    h[j] = hh;
    lo[j] = f2bf(v[j] - bf2f(hh));
  }
  ((us4*)oh)[i] = h;
  ((us4*)ol)[i] = lo;
}

// ---------------- transpose + hi/lo decompose: 4 fp32 1024x1024 weights ----------
__global__ __launch_bounds__(256) void transpose_decomp4(
    const float* __restrict__ w0, const float* __restrict__ w1,
    const float* __restrict__ w2, const float* __restrict__ w3,
    unsigned short* __restrict__ wt) {
  __shared__ float tile[32][33];
  int z = blockIdx.z;
  const float* in = (z == 0) ? w0 : (z == 1) ? w1 : (z == 2) ? w2 : w3;
  unsigned short* oh = wt + (size_t)(z * 2) * 1024 * 1024;
  unsigned short* ol = oh + (size_t)1024 * 1024;
  int tx = threadIdx.x, ty = threadIdx.y;   // block (32,8)
  int x  = blockIdx.x * 32 + tx;
  int y0 = blockIdx.y * 32;
  for (int i = ty; i < 32; i += 8)
    tile[i][tx] = in[(size_t)(y0 + i) * HD + x];
  __syncthreads();
  int x2 = y0 + tx;               // k index after transpose
  int y2 = blockIdx.x * 32;       // n index after transpose
  for (int i = ty; i < 32; i += 8) {
    float v = tile[tx][i];
    unsigned short h = f2bf(v);
    oh[(size_t)(y2 + i) * HD + x2] = h;
    ol[(size_t)(y2 + i) * HD + x2] = f2bf(v - bf2f(h));
  }
}

// ---------------- batched QKV GEMM ----------------
// z=0: q = inputs@Wq^T+bq ; z=1: k = context@Wk ; z=2: v = context@Wv.
// 128x128 tile, 256 thr = 4 waves (2m x 2n), wave tile 64x64 (4x4 accs).
// Split-precision: acc += Ah*Bh + Al*Bh + Ah*Bl.
// LDS: 4 planes [128][32], XOR-swizzled chunks (slot c of row r holds global
// chunk c ^ ((r>>1)&3)); wave w stages plane w via 8x global_load_lds width 16.
__global__ __launch_bounds__(256, 3) void gemm_qkv(
    const unsigned short* __restrict__ Ih, const unsigned short* __restrict__ Il,
    const unsigned short* __restrict__ Ch, const unsigned short* __restrict__ Cl,
    const unsigned short* __restrict__ wt,
    const float* __restrict__ bq, const float* __restrict__ bk, const float* __restrict__ bv,
    float* __restrict__ qo, float* __restrict__ ko, float* __restrict__ vo) {
  __shared__ __align__(16) unsigned short lds[4][128][32];
  const int K = HD, N = HD;
  const size_t P = (size_t)1024 * 1024;
  int z  = blockIdx.z;
  const unsigned short* Ah = z ? Ch : Ih;
  const unsigned short* Al = z ? Cl : Il;
  const unsigned short* Bth = wt + (size_t)(2 * z) * P;
  const unsigned short* Btl = Bth + P;
  const float* bias = (z == 0) ? bq : (z == 1) ? bk : bv;
  float* C = (z == 0) ? qo : (z == 1) ? ko : vo;

  int m0 = blockIdx.x * 128;
  int n0 = blockIdx.y * 128;
  int tid  = threadIdx.x;
  int lane = tid & 63;
  int w    = tid >> 6;            // 0..3 ; wave w stages plane w
  int quad = lane >> 4;
  int l16  = lane & 15;
  int wm = (w >> 1) * 64;         // 0 / 64
  int wn = (w & 1) * 64;          // 0 / 64

  // staging source for this wave's plane: row = seg*16 + lr, slot = lane&3,
  // global chunk g = slot ^ ((lr>>1)&3)  (seg*16 contributes 0 mod 4 to (row>>1)&3)
  int lr = lane >> 2;             // 0..15
  int g  = (lane & 3) ^ ((lr >> 1) & 3);
  const unsigned short* srcb;
  if (w == 0)      srcb = Ah  + (size_t)(m0 + lr) * K + g * 8;
  else if (w == 1) srcb = Al  + (size_t)(m0 + lr) * K + g * 8;
  else if (w == 2) srcb = Bth + (size_t)(n0 + lr) * K + g * 8;
  else             srcb = Btl + (size_t)(n0 + lr) * K + g * 8;
  unsigned short* dstb = &lds[w][0][0];

  f32x4 acc[4][4];
#pragma unroll
  for (int t = 0; t < 4; ++t)
#pragma unroll
    for (int u = 0; u < 4; ++u) acc[t][u] = (f32x4){0.f, 0.f, 0.f, 0.f};

  int sl8 = (quad ^ ((l16 >> 1) & 3)) * 8;   // swizzled chunk offset (shorts)

  for (int k0 = 0; k0 < K; k0 += 32) {
    __syncthreads();              // previous iter's frag reads complete
#pragma unroll
    for (int seg = 0; seg < 8; ++seg)
      gload16(srcb + (size_t)seg * 16 * K + k0, dstb + seg * 16 * 32);
    __syncthreads();              // staged data visible

    short8 ah[4], al[4], bh[4], bl[4];
#pragma unroll
    for (int t = 0; t < 4; ++t) {
      int rr = wm + t * 16 + l16;
      ah[t] = *(const short8*)&lds[0][rr][sl8];
      al[t] = *(const short8*)&lds[1][rr][sl8];
    }
#pragma unroll
    for (int u = 0; u < 4; ++u) {
      int rn = wn + u * 16 + l16;
      bh[u] = *(const short8*)&lds[2][rn][sl8];
      bl[u] = *(const short8*)&lds[3][rn][sl8];
    }
#pragma unroll
    for (int t = 0; t < 4; ++t)
#pragma unroll
      for (int u = 0; u < 4; ++u)
        acc[t][u] = __builtin_amdgcn_mfma_f32_16x16x32_bf16(ah[t], bh[u], acc[t][u], 0, 0, 0);
#pragma unroll
    for (int t = 0; t < 4; ++t)
#pragma unroll
      for (int u = 0; u < 4; ++u)
        acc[t][u] = __builtin_amdgcn_mfma_f32_16x16x32_bf16(al[t], bh[u], acc[t][u], 0, 0, 0);
#pragma unroll
    for (int t = 0; t < 4; ++t)
#pragma unroll
      for (int u = 0; u < 4; ++u)
        acc[t][u] = __builtin_amdgcn_mfma_f32_16x16x32_bf16(ah[t], bl[u], acc[t][u], 0, 0, 0);
  }

#pragma unroll
  for (int t = 0; t < 4; ++t) {
    int row = m0 + wm + t * 16 + quad * 4;
#pragma unroll
    for (int u = 0; u < 4; ++u) {
      int col = n0 + wn + u * 16 + l16;
      float bvv = bias[col];
#pragma unroll
      for (int i = 0; i < 4; ++i)
        C[(size_t)(row + i) * N + col] = acc[t][u][i] + bvv;
    }
  }
}

// ---------------- O GEMM: C[M,1024] = (Ah+Al) @ (Bh+Bl)^T + bias ------
// 128x128 tile, 512 thr = 8 waves (2m x 4n), wave 64x32 (4x2). (R3 structure,
// kept for the standalone 256-block dispatch where 8 waves/CU beats 4.)
__global__ __launch_bounds__(512) void gemm_split(
    const unsigned short* __restrict__ Ah, const unsigned short* __restrict__ Al,
    const unsigned short* __restrict__ Bth, const unsigned short* __restrict__ Btl,
    const float* __restrict__ bias, float* __restrict__ C) {
  __shared__ __align__(16) unsigned short lds[4][128][32];
  const int K = HD, N = HD;
  int m0 = blockIdx.x * 128;
  int n0 = blockIdx.y * 128;
  int tid = threadIdx.x;
  int lane = tid & 63;
  int w    = tid >> 6;            // 0..7
  int quad = lane >> 4;
  int l16  = lane & 15;
  int wm = (w >> 2) * 64;
  int wn = (w & 3) * 32;

  int lr = lane >> 2;
  int lc = lane & 3;
  int r  = w * 16 + lr;
  int g  = lc ^ ((r >> 1) & 3);
  const unsigned short* src[4];
  src[0] = Ah  + (size_t)(m0 + r) * K + g * 8;
  src[1] = Al  + (size_t)(m0 + r) * K + g * 8;
  src[2] = Bth + (size_t)(n0 + r) * K + g * 8;
  src[3] = Btl + (size_t)(n0 + r) * K + g * 8;
  unsigned short* dst[4];
#pragma unroll
  for (int p = 0; p < 4; ++p) dst[p] = &lds[p][w * 16][0];

  f32x4 acc[4][2];
#pragma unroll
  for (int t = 0; t < 4; ++t)
#pragma unroll
    for (int u = 0; u < 2; ++u) acc[t][u] = (f32x4){0.f, 0.f, 0.f, 0.f};

  int sl8 = (quad ^ ((l16 >> 1) & 3)) * 8;

  for (int k0 = 0; k0 < K; k0 += 32) {
    __syncthreads();
#pragma unroll
    for (int p = 0; p < 4; ++p) gload16(src[p] + k0, dst[p]);
    __syncthreads();

    short8 ah[4], al[4], bh[2], bl[2];
#pragma unroll
    for (int t = 0; t < 4; ++t) {
      int rr = wm + t * 16 + l16;
      ah[t] = *(const short8*)&lds[0][rr][sl8];
      al[t] = *(const short8*)&lds[1][rr][sl8];
    }
#pragma unroll
    for (int u = 0; u < 2; ++u) {
      int rn = wn + u * 16 + l16;
      bh[u] = *(const short8*)&lds[2][rn][sl8];
      bl[u] = *(const short8*)&lds[3][rn][sl8];
    }
#pragma unroll
    for (int t = 0; t < 4; ++t)
#pragma unroll
      for (int u = 0; u < 2; ++u)
        acc[t][u] = __builtin_amdgcn_mfma_f32_16x16x32_bf16(ah[t], bh[u], acc[t][u], 0, 0, 0);
#pragma unroll
    for (int t = 0; t < 4; ++t)
#pragma unroll
      for (int u = 0; u < 2; ++u)
        acc[t][u] = __builtin_amdgcn_mfma_f32_16x16x32_bf16(al[t], bh[u], acc[t][u], 0, 0, 0);
#pragma unroll
    for (int t = 0; t < 4; ++t)
#pragma unroll
      for (int u = 0; u < 2; ++u)
        acc[t][u] = __builtin_amdgcn_mfma_f32_16x16x32_bf16(ah[t], bl[u], acc[t][u], 0, 0, 0);
  }

#pragma unroll
  for (int t = 0; t < 4; ++t) {
    int row = m0 + wm + t * 16 + quad * 4;
#pragma unroll
    for (int u = 0; u < 2; ++u) {
      int col = n0 + wn + u * 16 + l16;
      float bv = bias[col];
#pragma unroll
      for (int i = 0; i < 4; ++i)
        C[(size_t)(row + i) * N + col] = acc[t][u][i] + bv;
    }
  }
}

// ---------------- fused RoPE + per-(b,s) head-attention ----------------
// Loads raw q,k rows, applies RoPE in LDS, then scores/softmax/ctx.
// ctx written as hi/lo bf16 planes in the transpose(0,2,1,3) scrambled layout.
__global__ __launch_bounds__(256) void attn_rope_k(
    const float* __restrict__ q, const float* __restrict__ kk, const float* __restrict__ v,
    float* __restrict__ attn_out,
    unsigned short* __restrict__ ctx_h, unsigned short* __restrict__ ctx_l) {
  __shared__ float qs[16][68], ks[16][68], vs[16][68], as[16][17];
  int m = blockIdx.x;            // b*S + s
  int tid = threadIdx.x;
  int s = m & (SEQ - 1);
  size_t base4 = (size_t)m * (HD / 4);
  {
    int h = tid >> 4, dd = (tid & 15) * 4;
    float4v qv = ((const float4v*)q)[base4 + tid];
    float4v kv = ((const float4v*)kk)[base4 + tid];
    float4v vv = ((const float4v*)v)[base4 + tid];
    *(float4v*)&qs[h][dd] = qv;
    *(float4v*)&ks[h][dd] = kv;
    *(float4v*)&vs[h][dd] = vv;
  }
  __syncthreads();
  // RoPE: pairs (d, d+512) over flat hidden -> (h, dd) with (h+8, dd)
#pragma unroll
  for (int d = tid; d < 512; d += 256) {
    float f = exp2f(-(float)d * 0.025952563241307517f);  // log2(10000)/512
    float th = (float)s * f;
    float sv, cv;
    __sincosf(th, &sv, &cv);
    // need accurate range reduction for th up to ~2047 rad: use sincosf
    sincosf(th, &sv, &cv);
    int h1 = d >> 6, dd = d & 63, h2 = h1 + 8;
    float q1 = qs[h1][dd], q2 = qs[h2][dd];
    qs[h1][dd] = q1 * cv - q2 * sv;
    qs[h2][dd] = q2 * cv + q1 * sv;
    float k1 = ks[h1][dd], k2 = ks[h2][dd];
    ks[h1][dd] = k1 * cv - k2 * sv;
    ks[h2][dd] = k2 * cv + k1 * sv;
  }
  __syncthreads();
  int h = tid >> 4, t = tid & 15;
  float sc = 0.f;
#pragma unroll
  for (int d = 0; d < 64; ++d) sc = fmaf(qs[h][d], ks[t][d], sc);
  sc *= 0.125f;   // 1/sqrt(64)
  float mx = sc;
  mx = fmaxf(mx, __shfl_xor(mx, 1));
  mx = fmaxf(mx, __shfl_xor(mx, 2));
  mx = fmaxf(mx, __shfl_xor(mx, 4));
  mx = fmaxf(mx, __shfl_xor(mx, 8));
  float e = expf(sc - mx);
  float sum = e;
  sum += __shfl_xor(sum, 1);
  sum += __shfl_xor(sum, 2);
  sum += __shfl_xor(sum, 4);
  sum += __shfl_xor(sum, 8);
  float a = e / sum;
  attn_out[(size_t)m * 256 + tid] = a;
  as[h][t] = a;
  __syncthreads();
  int b = m >> 11;
  for (int j = tid; j < 1024; j += 256) {
    int h2 = j >> 6, d = j & 63;
    float c = 0.f;
#pragma unroll
    for (int t2 = 0; t2 < 16; ++t2) c = fmaf(as[h2][t2], vs[t2][d], c);
    int row = b * SEQ + h2 * 128 + (s >> 4);
    int col = (s & 15) * 64 + d;
    size_t off = (size_t)row * HD + col;
    unsigned short hh = f2bf(c);
    ctx_h[off] = hh;
    ctx_l[off] = f2bf(c - bf2f(hh));
  }
}

extern "C" void kernel_launch(void* const* d_in, const int* in_sizes, int n_in,
                              void* d_out, int out_size, void* d_ws, size_t ws_size,
                              hipStream_t stream) {
  const float* inputs  = (const float*)d_in[0];
  const float* context = (const float*)d_in[1];
  const float* Wq = (const float*)d_in[2];
  const float* bq = (const float*)d_in[3];
  const float* Wk = (const float*)d_in[4];
  const float* bk = (const float*)d_in[5];
  const float* Wv = (const float*)d_in[6];
  const float* bv = (const float*)d_in[7];
  const float* Wo = (const float*)d_in[8];
  const float* bo = (const float*)d_in[9];

  float* out  = (float*)d_out;                     // [2,2048,1024] flat
  float* attn = out + (size_t)4096 * 1024;         // [2,2048,16,16] flat

  const size_t MB = 1ull << 20;
  char* wsb = (char*)d_ws;
  float* q = (float*)(wsb + 0 * MB);               // 16 MB
  float* k = (float*)(wsb + 16 * MB);              // 16 MB
  unsigned short* wt = (unsigned short*)(wsb + 32 * MB);   // 8 planes x 2 MB
  unsigned short* Ih = (unsigned short*)(wsb + 48 * MB);   // 8 MB
  unsigned short* Il = (unsigned short*)(wsb + 56 * MB);   // 8 MB
  unsigned short* Ch = (unsigned short*)(wsb + 64 * MB);   // 8 MB
  unsigned short* Cl = (unsigned short*)(wsb + 72 * MB);   // 8 MB
  float* v = (float*)(wsb + 48 * MB);              // aliases Ih/Il (dead after QKV gemm)
  unsigned short* ctxh = Ch;                       // alias (dead after QKV gemm)
  unsigned short* ctxl = Cl;

  decomp2<<<dim3(4096, 2), 256, 0, stream>>>(inputs, context, Ih, Il, Ch, Cl);
  transpose_decomp4<<<dim3(32, 32, 4), dim3(32, 8), 0, stream>>>(Wq, Wk, Wv, Wo, wt);

  gemm_qkv<<<dim3(32, 8, 3), 256, 0, stream>>>(Ih, Il, Ch, Cl, wt, bq, bk, bv, q, k, v);

  attn_rope_k<<<4096, 256, 0, stream>>>(q, k, v, attn, ctxh, ctxl);

  const size_t P = (size_t)1024 * 1024;
  gemm_split<<<dim3(32, 8), 512, 0, stream>>>(ctxh, ctxl, wt + 6 * P, wt + 7 * P, bo, out);
}

// Round 5
// 221.415 us; speedup vs baseline: 1.4397x; 1.0856x over previous
//
#include <hip/hip_runtime.h>
#include <hip/hip_bf16.h>
#include <cstdint>

typedef __attribute__((ext_vector_type(8))) short short8;
typedef __attribute__((ext_vector_type(4))) float f32x4;
typedef __attribute__((ext_vector_type(4))) float float4v;
typedef __attribute__((ext_vector_type(4))) unsigned short us4;

#define HD 1024
#define SEQ 2048

// fp32 -> bf16 (round-to-nearest-even), raw bits; inputs are finite.
__device__ __forceinline__ unsigned short f2bf(float f) {
  uint32_t u = __builtin_bit_cast(uint32_t, f);
  return (unsigned short)((u + 0x7FFFu + ((u >> 16) & 1u)) >> 16);
}
__device__ __forceinline__ float bf2f(unsigned short s) {
  return __builtin_bit_cast(float, (uint32_t)s << 16);
}

// async global->LDS, 16B per lane, dest = wave-uniform base + lane*16
__device__ __forceinline__ void gload16(const unsigned short* g, unsigned short* l) {
  __builtin_amdgcn_global_load_lds(
      (const __attribute__((address_space(1))) void*)g,
      (__attribute__((address_space(3))) void*)l, 16, 0, 0);
}

// ---------------- fused prep ----------------
// bx in [0,4096):    hi/lo decompose of inputs (bx<2048) / context
// bx in [4096,8192): transpose + hi-decompose of weight (bx-4096)>>10
// bx in [8192,9216): zero d_out's `out` region (16 MB)
__global__ __launch_bounds__(256) void prep(
    const float* __restrict__ X, const float* __restrict__ Y,
    const float* __restrict__ w0, const float* __restrict__ w1,
    const float* __restrict__ w2, const float* __restrict__ w3,
    unsigned short* __restrict__ Xh, unsigned short* __restrict__ Xl,
    unsigned short* __restrict__ Yh, unsigned short* __restrict__ Yl,
    unsigned short* __restrict__ wt, float* __restrict__ outz) {
  __shared__ float tile[32][33];
  int bx = blockIdx.x;
  int tid = threadIdx.x;
  if (bx < 4096) {
    const float* src = (bx >= 2048) ? Y : X;
    unsigned short* oh = (bx >= 2048) ? Yh : Xh;
    unsigned short* ol = (bx >= 2048) ? Yl : Xl;
    int i0 = (bx & 2047) * 512 + tid;
#pragma unroll
    for (int r = 0; r < 2; ++r) {
      int i = i0 + r * 256;
      float4v v = ((const float4v*)src)[i];
      us4 h, lo;
#pragma unroll
      for (int j = 0; j < 4; ++j) {
        unsigned short hh = f2bf(v[j]);
        h[j] = hh;
        lo[j] = f2bf(v[j] - bf2f(hh));
      }
      ((us4*)oh)[i] = h;
      ((us4*)ol)[i] = lo;
    }
  } else if (bx < 8192) {
    int t = bx - 4096;
    int z = t >> 10;
    int rem = t & 1023;
    int bxx = rem & 31, byy = rem >> 5;
    const float* in = (z == 0) ? w0 : (z == 1) ? w1 : (z == 2) ? w2 : w3;
    unsigned short* oh = wt + (size_t)z * 1024 * 1024;
    int tx = tid & 31, ty = tid >> 5;
    int x = bxx * 32 + tx;
    int y0 = byy * 32;
    for (int i = ty; i < 32; i += 8)
      tile[i][tx] = in[(size_t)(y0 + i) * HD + x];
    __syncthreads();
    int x2 = y0 + tx;               // k index after transpose
    int y2 = bxx * 32;              // n index after transpose
    for (int i = ty; i < 32; i += 8)
      oh[(size_t)(y2 + i) * HD + x2] = f2bf(tile[tx][i]);
  } else {
    int i0 = (bx - 8192) * 1024 + tid;
    float4v zv = {0.f, 0.f, 0.f, 0.f};
#pragma unroll
    for (int r = 0; r < 4; ++r)
      ((float4v*)outz)[i0 + r * 256] = zv;
  }
}

// ---------------- batched QKV GEMM, 2-pass split ----------------
// z=0: q = inputs@Wq+bq ; z=1: k = context@Wk+bk ; z=2: v = context@Wv+bv.
// acc += Ah*Bh + Al*Bh  (B-residual dropped; A hi/lo planes).
// 128x128 tile, 256 thr = 4 waves (2m x 2n), wave tile 64x64 (4x4 accs).
// LDS: 3 planes [128][32], XOR-swizzled chunks (slot c of row r holds global
// chunk c ^ ((r>>1)&3)); wave w stages segs {w, w+4} of each plane, width-16 DMA.
__global__ __launch_bounds__(256, 3) void gemm_qkv(
    const unsigned short* __restrict__ Ih, const unsigned short* __restrict__ Il,
    const unsigned short* __restrict__ Ch, const unsigned short* __restrict__ Cl,
    const unsigned short* __restrict__ wt,
    const float* __restrict__ bq, const float* __restrict__ bk, const float* __restrict__ bv,
    float* __restrict__ qo, float* __restrict__ ko, float* __restrict__ vo) {
  __shared__ __align__(16) unsigned short lds[3][128][32];
  const int K = HD, N = HD;
  const size_t P = (size_t)1024 * 1024;
  int z  = blockIdx.z;
  const unsigned short* Ah = z ? Ch : Ih;
  const unsigned short* Al = z ? Cl : Il;
  const unsigned short* Bth = wt + (size_t)z * P;
  const float* bias = (z == 0) ? bq : (z == 1) ? bk : bv;
  float* C = (z == 0) ? qo : (z == 1) ? ko : vo;

  int m0 = blockIdx.x * 128;
  int n0 = blockIdx.y * 128;
  int tid  = threadIdx.x;
  int lane = tid & 63;
  int w    = tid >> 6;            // 0..3
  int quad = lane >> 4;
  int l16  = lane & 15;
  int wm = (w >> 1) * 64;
  int wn = (w & 1) * 64;

  int lr = lane >> 2;             // 0..15
  int g  = (lane & 3) ^ ((lr >> 1) & 3);
  const unsigned short* sp0 = Ah  + (size_t)(m0 + lr) * K + g * 8;
  const unsigned short* sp1 = Al  + (size_t)(m0 + lr) * K + g * 8;
  const unsigned short* sp2 = Bth + (size_t)(n0 + lr) * K + g * 8;
  int s0 = w * 16;                // rows s0..s0+15
  int s1 = (w + 4) * 16;          // rows s1..s1+15

  f32x4 acc[4][4];
#pragma unroll
  for (int t = 0; t < 4; ++t)
#pragma unroll
    for (int u = 0; u < 4; ++u) acc[t][u] = (f32x4){0.f, 0.f, 0.f, 0.f};

  int sl8 = (quad ^ ((l16 >> 1) & 3)) * 8;

  for (int k0 = 0; k0 < K; k0 += 32) {
    __syncthreads();
    gload16(sp0 + (size_t)s0 * K + k0, &lds[0][s0][0]);
    gload16(sp0 + (size_t)s1 * K + k0, &lds[0][s1][0]);
    gload16(sp1 + (size_t)s0 * K + k0, &lds[1][s0][0]);
    gload16(sp1 + (size_t)s1 * K + k0, &lds[1][s1][0]);
    gload16(sp2 + (size_t)s0 * K + k0, &lds[2][s0][0]);
    gload16(sp2 + (size_t)s1 * K + k0, &lds[2][s1][0]);
    __syncthreads();

    short8 ah[4], al[4], bh[4];
#pragma unroll
    for (int t = 0; t < 4; ++t) {
      int rr = wm + t * 16 + l16;
      ah[t] = *(const short8*)&lds[0][rr][sl8];
      al[t] = *(const short8*)&lds[1][rr][sl8];
    }
#pragma unroll
    for (int u = 0; u < 4; ++u)
      bh[u] = *(const short8*)&lds[2][wn + u * 16 + l16][sl8];
#pragma unroll
    for (int t = 0; t < 4; ++t)
#pragma unroll
      for (int u = 0; u < 4; ++u)
        acc[t][u] = __builtin_amdgcn_mfma_f32_16x16x32_bf16(ah[t], bh[u], acc[t][u], 0, 0, 0);
#pragma unroll
    for (int t = 0; t < 4; ++t)
#pragma unroll
      for (int u = 0; u < 4; ++u)
        acc[t][u] = __builtin_amdgcn_mfma_f32_16x16x32_bf16(al[t], bh[u], acc[t][u], 0, 0, 0);
  }

#pragma unroll
  for (int t = 0; t < 4; ++t) {
    int row = m0 + wm + t * 16 + quad * 4;
#pragma unroll
    for (int u = 0; u < 4; ++u) {
      int col = n0 + wn + u * 16 + l16;
      float bvv = bias[col];
#pragma unroll
      for (int i = 0; i < 4; ++i)
        C[(size_t)(row + i) * N + col] = acc[t][u][i] + bvv;
    }
  }
}

// ---------------- O GEMM, 2-pass split, split-K=2, atomic epilogue ----------------
// z in {0,1}: K-range [z*512, z*512+512). out must be pre-zeroed; z==0 adds bias.
__global__ __launch_bounds__(256, 3) void gemm_o_splitk(
    const unsigned short* __restrict__ Ah, const unsigned short* __restrict__ Al,
    const unsigned short* __restrict__ Bth,
    const float* __restrict__ bias, float* __restrict__ C) {
  __shared__ __align__(16) unsigned short lds[3][128][32];
  const int K = HD, N = HD;
  int z  = blockIdx.z;
  int m0 = blockIdx.x * 128;
  int n0 = blockIdx.y * 128;
  int tid  = threadIdx.x;
  int lane = tid & 63;
  int w    = tid >> 6;
  int quad = lane >> 4;
  int l16  = lane & 15;
  int wm = (w >> 1) * 64;
  int wn = (w & 1) * 64;

  int lr = lane >> 2;
  int g  = (lane & 3) ^ ((lr >> 1) & 3);
  const unsigned short* sp0 = Ah  + (size_t)(m0 + lr) * K + g * 8;
  const unsigned short* sp1 = Al  + (size_t)(m0 + lr) * K + g * 8;
  const unsigned short* sp2 = Bth + (size_t)(n0 + lr) * K + g * 8;
  int s0 = w * 16;
  int s1 = (w + 4) * 16;

  f32x4 acc[4][4];
#pragma unroll
  for (int t = 0; t < 4; ++t)
#pragma unroll
    for (int u = 0; u < 4; ++u) acc[t][u] = (f32x4){0.f, 0.f, 0.f, 0.f};

  int sl8 = (quad ^ ((l16 >> 1) & 3)) * 8;

  int kend = z * 512 + 512;
  for (int k0 = z * 512; k0 < kend; k0 += 32) {
    __syncthreads();
    gload16(sp0 + (size_t)s0 * K + k0, &lds[0][s0][0]);
    gload16(sp0 + (size_t)s1 * K + k0, &lds[0][s1][0]);
    gload16(sp1 + (size_t)s0 * K + k0, &lds[1][s0][0]);
    gload16(sp1 + (size_t)s1 * K + k0, &lds[1][s1][0]);
    gload16(sp2 + (size_t)s0 * K + k0, &lds[2][s0][0]);
    gload16(sp2 + (size_t)s1 * K + k0, &lds[2][s1][0]);
    __syncthreads();

    short8 ah[4], al[4], bh[4];
#pragma unroll
    for (int t = 0; t < 4; ++t) {
      int rr = wm + t * 16 + l16;
      ah[t] = *(const short8*)&lds[0][rr][sl8];
      al[t] = *(const short8*)&lds[1][rr][sl8];
    }
#pragma unroll
    for (int u = 0; u < 4; ++u)
      bh[u] = *(const short8*)&lds[2][wn + u * 16 + l16][sl8];
#pragma unroll
    for (int t = 0; t < 4; ++t)
#pragma unroll
      for (int u = 0; u < 4; ++u)
        acc[t][u] = __builtin_amdgcn_mfma_f32_16x16x32_bf16(ah[t], bh[u], acc[t][u], 0, 0, 0);
#pragma unroll
    for (int t = 0; t < 4; ++t)
#pragma unroll
      for (int u = 0; u < 4; ++u)
        acc[t][u] = __builtin_amdgcn_mfma_f32_16x16x32_bf16(al[t], bh[u], acc[t][u], 0, 0, 0);
  }

#pragma unroll
  for (int t = 0; t < 4; ++t) {
    int row = m0 + wm + t * 16 + quad * 4;
#pragma unroll
    for (int u = 0; u < 4; ++u) {
      int col = n0 + wn + u * 16 + l16;
      float bvv = (z == 0) ? bias[col] : 0.f;
#pragma unroll
      for (int i = 0; i < 4; ++i)
        atomicAdd(&C[(size_t)(row + i) * N + col], acc[t][u][i] + bvv);
    }
  }
}

// ---------------- fused RoPE + per-(b,s) head-attention ----------------
__global__ __launch_bounds__(256) void attn_rope_k(
    const float* __restrict__ q, const float* __restrict__ kk, const float* __restrict__ v,
    float* __restrict__ attn_out,
    unsigned short* __restrict__ ctx_h, unsigned short* __restrict__ ctx_l) {
  __shared__ float qs[16][68], ks[16][68], vs[16][68], as[16][17];
  int m = blockIdx.x;            // b*S + s
  int tid = threadIdx.x;
  int s = m & (SEQ - 1);
  size_t base4 = (size_t)m * (HD / 4);
  {
    int h = tid >> 4, dd = (tid & 15) * 4;
    float4v qv = ((const float4v*)q)[base4 + tid];
    float4v kv = ((const float4v*)kk)[base4 + tid];
    float4v vv = ((const float4v*)v)[base4 + tid];
    *(float4v*)&qs[h][dd] = qv;
    *(float4v*)&ks[h][dd] = kv;
    *(float4v*)&vs[h][dd] = vv;
  }
  __syncthreads();
  // RoPE: pairs (d, d+512) over flat hidden -> (h, dd) with (h+8, dd)
#pragma unroll
  for (int d = tid; d < 512; d += 256) {
    float f = exp2f(-(float)d * 0.025952563241307517f);  // log2(10000)/512
    float th = (float)s * f;
    float sv, cv;
    sincosf(th, &sv, &cv);      // accurate range reduction (th up to ~2047 rad)
    int h1 = d >> 6, dd = d & 63, h2 = h1 + 8;
    float q1 = qs[h1][dd], q2 = qs[h2][dd];
    qs[h1][dd] = q1 * cv - q2 * sv;
    qs[h2][dd] = q2 * cv + q1 * sv;
    float k1 = ks[h1][dd], k2 = ks[h2][dd];
    ks[h1][dd] = k1 * cv - k2 * sv;
    ks[h2][dd] = k2 * cv + k1 * sv;
  }
  __syncthreads();
  int h = tid >> 4, t = tid & 15;
  float sc = 0.f;
#pragma unroll
  for (int d = 0; d < 64; ++d) sc = fmaf(qs[h][d], ks[t][d], sc);
  sc *= 0.125f;   // 1/sqrt(64)
  float mx = sc;
  mx = fmaxf(mx, __shfl_xor(mx, 1));
  mx = fmaxf(mx, __shfl_xor(mx, 2));
  mx = fmaxf(mx, __shfl_xor(mx, 4));
  mx = fmaxf(mx, __shfl_xor(mx, 8));
  float e = expf(sc - mx);
  float sum = e;
  sum += __shfl_xor(sum, 1);
  sum += __shfl_xor(sum, 2);
  sum += __shfl_xor(sum, 4);
  sum += __shfl_xor(sum, 8);
  float a = e / sum;
  attn_out[(size_t)m * 256 + tid] = a;
  as[h][t] = a;
  __syncthreads();
  int b = m >> 11;
  for (int j = tid; j < 1024; j += 256) {
    int h2 = j >> 6, d = j & 63;
    float c = 0.f;
#pragma unroll
    for (int t2 = 0; t2 < 16; ++t2) c = fmaf(as[h2][t2], vs[t2][d], c);
    int row = b * SEQ + h2 * 128 + (s >> 4);
    int col = (s & 15) * 64 + d;
    size_t off = (size_t)row * HD + col;
    unsigned short hh = f2bf(c);
    ctx_h[off] = hh;
    ctx_l[off] = f2bf(c - bf2f(hh));
  }
}

extern "C" void kernel_launch(void* const* d_in, const int* in_sizes, int n_in,
                              void* d_out, int out_size, void* d_ws, size_t ws_size,
                              hipStream_t stream) {
  const float* inputs  = (const float*)d_in[0];
  const float* context = (const float*)d_in[1];
  const float* Wq = (const float*)d_in[2];
  const float* bq = (const float*)d_in[3];
  const float* Wk = (const float*)d_in[4];
  const float* bk = (const float*)d_in[5];
  const float* Wv = (const float*)d_in[6];
  const float* bv = (const float*)d_in[7];
  const float* Wo = (const float*)d_in[8];
  const float* bo = (const float*)d_in[9];

  float* out  = (float*)d_out;                     // [2,2048,1024] flat
  float* attn = out + (size_t)4096 * 1024;         // [2,2048,16,16] flat

  const size_t MB = 1ull << 20;
  char* wsb = (char*)d_ws;
  float* q = (float*)(wsb + 0 * MB);               // 16 MB
  float* k = (float*)(wsb + 16 * MB);              // 16 MB
  unsigned short* wt = (unsigned short*)(wsb + 32 * MB);   // 4 hi planes x 2 MB
  unsigned short* Ih = (unsigned short*)(wsb + 40 * MB);   // 8 MB
  unsigned short* Il = (unsigned short*)(wsb + 48 * MB);   // 8 MB
  unsigned short* Ch = (unsigned short*)(wsb + 56 * MB);   // 8 MB
  unsigned short* Cl = (unsigned short*)(wsb + 64 * MB);   // 8 MB
  float* v = (float*)(wsb + 40 * MB);              // aliases Ih/Il (dead after QKV gemm)
  unsigned short* ctxh = Ch;                       // alias (dead after QKV gemm)
  unsigned short* ctxl = Cl;

  prep<<<9216, 256, 0, stream>>>(inputs, context, Wq, Wk, Wv, Wo,
                                 Ih, Il, Ch, Cl, wt, out);

  gemm_qkv<<<dim3(32, 8, 3), 256, 0, stream>>>(Ih, Il, Ch, Cl, wt, bq, bk, bv, q, k, v);

  attn_rope_k<<<4096, 256, 0, stream>>>(q, k, v, attn, ctxh, ctxl);

  const size_t P = (size_t)1024 * 1024;
  gemm_o_splitk<<<dim3(32, 8, 2), 256, 0, stream>>>(ctxh, ctxl, wt + 3 * P, bo, out);
}

// Round 6
// 190.219 us; speedup vs baseline: 1.6758x; 1.1640x over previous
//
#include <hip/hip_runtime.h>
#include <hip/hip_bf16.h>
#include <cstdint>

typedef __attribute__((ext_vector_type(8))) short short8;
typedef __attribute__((ext_vector_type(4))) float f32x4;
typedef __attribute__((ext_vector_type(4))) float float4v;
typedef __attribute__((ext_vector_type(4))) unsigned short us4;

#define HD 1024
#define SEQ 2048

// fp32 -> bf16 (round-to-nearest-even), raw bits; inputs are finite.
__device__ __forceinline__ unsigned short f2bf(float f) {
  uint32_t u = __builtin_bit_cast(uint32_t, f);
  return (unsigned short)((u + 0x7FFFu + ((u >> 16) & 1u)) >> 16);
}
__device__ __forceinline__ float bf2f(unsigned short s) {
  return __builtin_bit_cast(float, (uint32_t)s << 16);
}

// async global->LDS, 16B per lane, dest = wave-uniform base + lane*16
__device__ __forceinline__ void gload16(const unsigned short* g, unsigned short* l) {
  __builtin_amdgcn_global_load_lds(
      (const __attribute__((address_space(1))) void*)g,
      (__attribute__((address_space(3))) void*)l, 16, 0, 0);
}

// ---------------- fused prep ----------------
// bx in [0,4096):    bf16-hi cast of inputs (bx<2048) / context
// bx in [4096,8192): transpose + bf16-hi cast of weight (bx-4096)>>10
// bx in [8192,9216): zero d_out's `out` region (16 MB)
__global__ __launch_bounds__(256) void prep(
    const float* __restrict__ X, const float* __restrict__ Y,
    const float* __restrict__ w0, const float* __restrict__ w1,
    const float* __restrict__ w2, const float* __restrict__ w3,
    unsigned short* __restrict__ Xh, unsigned short* __restrict__ Yh,
    unsigned short* __restrict__ wt, float* __restrict__ outz) {
  __shared__ float tile[32][33];
  int bx = blockIdx.x;
  int tid = threadIdx.x;
  if (bx < 4096) {
    const float* src = (bx >= 2048) ? Y : X;
    unsigned short* oh = (bx >= 2048) ? Yh : Xh;
    int i0 = (bx & 2047) * 512 + tid;
#pragma unroll
    for (int r = 0; r < 2; ++r) {
      int i = i0 + r * 256;
      float4v v = ((const float4v*)src)[i];
      us4 h;
#pragma unroll
      for (int j = 0; j < 4; ++j) h[j] = f2bf(v[j]);
      ((us4*)oh)[i] = h;
    }
  } else if (bx < 8192) {
    int t = bx - 4096;
    int z = t >> 10;
    int rem = t & 1023;
    int bxx = rem & 31, byy = rem >> 5;
    const float* in = (z == 0) ? w0 : (z == 1) ? w1 : (z == 2) ? w2 : w3;
    unsigned short* oh = wt + (size_t)z * 1024 * 1024;
    int tx = tid & 31, ty = tid >> 5;
    int x = bxx * 32 + tx;
    int y0 = byy * 32;
    for (int i = ty; i < 32; i += 8)
      tile[i][tx] = in[(size_t)(y0 + i) * HD + x];
    __syncthreads();
    int x2 = y0 + tx;               // k index after transpose
    int y2 = bxx * 32;              // n index after transpose
    for (int i = ty; i < 32; i += 8)
      oh[(size_t)(y2 + i) * HD + x2] = f2bf(tile[tx][i]);
  } else {
    int i0 = (bx - 8192) * 1024 + tid;
    float4v zv = {0.f, 0.f, 0.f, 0.f};
#pragma unroll
    for (int r = 0; r < 4; ++r)
      ((float4v*)outz)[i0 + r * 256] = zv;
  }
}

// ---------------- batched QKV GEMM, pure bf16 ----------------
// z=0: q = inputs@Wq+bq ; z=1: k = context@Wk+bk ; z=2: v = context@Wv+bv.
// Output bf16. 128x128 tile, 256 thr = 4 waves (2m x 2n), wave tile 64x64.
// LDS: 2 planes [128][32], XOR-swizzled chunks (slot c of row r holds global
// chunk c ^ ((r>>1)&3)); wave w stages segs {w, w+4} of each plane via width-16 DMA.
__global__ __launch_bounds__(256, 3) void gemm_qkv(
    const unsigned short* __restrict__ Ih, const unsigned short* __restrict__ Ch,
    const unsigned short* __restrict__ wt,
    const float* __restrict__ bq, const float* __restrict__ bk, const float* __restrict__ bv,
    unsigned short* __restrict__ qo, unsigned short* __restrict__ ko,
    unsigned short* __restrict__ vo) {
  __shared__ __align__(16) unsigned short lds[2][128][32];
  const int K = HD, N = HD;
  const size_t P = (size_t)1024 * 1024;
  int z  = blockIdx.z;
  const unsigned short* Ah = z ? Ch : Ih;
  const unsigned short* Bth = wt + (size_t)z * P;
  const float* bias = (z == 0) ? bq : (z == 1) ? bk : bv;
  unsigned short* C = (z == 0) ? qo : (z == 1) ? ko : vo;

  int m0 = blockIdx.x * 128;
  int n0 = blockIdx.y * 128;
  int tid  = threadIdx.x;
  int lane = tid & 63;
  int w    = tid >> 6;            // 0..3
  int quad = lane >> 4;
  int l16  = lane & 15;
  int wm = (w >> 1) * 64;
  int wn = (w & 1) * 64;

  int lr = lane >> 2;             // 0..15
  int g  = (lane & 3) ^ ((lr >> 1) & 3);
  const unsigned short* sp0 = Ah  + (size_t)(m0 + lr) * K + g * 8;
  const unsigned short* sp1 = Bth + (size_t)(n0 + lr) * K + g * 8;
  int s0 = w * 16;                // rows s0..s0+15
  int s1 = (w + 4) * 16;          // rows s1..s1+15

  f32x4 acc[4][4];
#pragma unroll
  for (int t = 0; t < 4; ++t)
#pragma unroll
    for (int u = 0; u < 4; ++u) acc[t][u] = (f32x4){0.f, 0.f, 0.f, 0.f};

  int sl8 = (quad ^ ((l16 >> 1) & 3)) * 8;

  for (int k0 = 0; k0 < K; k0 += 32) {
    __syncthreads();
    gload16(sp0 + (size_t)s0 * K + k0, &lds[0][s0][0]);
    gload16(sp0 + (size_t)s1 * K + k0, &lds[0][s1][0]);
    gload16(sp1 + (size_t)s0 * K + k0, &lds[1][s0][0]);
    gload16(sp1 + (size_t)s1 * K + k0, &lds[1][s1][0]);
    __syncthreads();

    short8 ah[4], bh[4];
#pragma unroll
    for (int t = 0; t < 4; ++t)
      ah[t] = *(const short8*)&lds[0][wm + t * 16 + l16][sl8];
#pragma unroll
    for (int u = 0; u < 4; ++u)
      bh[u] = *(const short8*)&lds[1][wn + u * 16 + l16][sl8];
#pragma unroll
    for (int t = 0; t < 4; ++t)
#pragma unroll
      for (int u = 0; u < 4; ++u)
        acc[t][u] = __builtin_amdgcn_mfma_f32_16x16x32_bf16(ah[t], bh[u], acc[t][u], 0, 0, 0);
  }

#pragma unroll
  for (int t = 0; t < 4; ++t) {
    int row = m0 + wm + t * 16 + quad * 4;
#pragma unroll
    for (int u = 0; u < 4; ++u) {
      int col = n0 + wn + u * 16 + l16;
      float bvv = bias[col];
#pragma unroll
      for (int i = 0; i < 4; ++i)
        C[(size_t)(row + i) * N + col] = f2bf(acc[t][u][i] + bvv);
    }
  }
}

// ---------------- O GEMM, pure bf16, split-K=2, atomic epilogue ----------------
// z in {0,1}: K-range [z*512, z*512+512). out pre-zeroed; z==0 adds bias.
__global__ __launch_bounds__(256, 3) void gemm_o_splitk(
    const unsigned short* __restrict__ Ah, const unsigned short* __restrict__ Bth,
    const float* __restrict__ bias, float* __restrict__ C) {
  __shared__ __align__(16) unsigned short lds[2][128][32];
  const int K = HD, N = HD;
  int z  = blockIdx.z;
  int m0 = blockIdx.x * 128;
  int n0 = blockIdx.y * 128;
  int tid  = threadIdx.x;
  int lane = tid & 63;
  int w    = tid >> 6;
  int quad = lane >> 4;
  int l16  = lane & 15;
  int wm = (w >> 1) * 64;
  int wn = (w & 1) * 64;

  int lr = lane >> 2;
  int g  = (lane & 3) ^ ((lr >> 1) & 3);
  const unsigned short* sp0 = Ah  + (size_t)(m0 + lr) * K + g * 8;
  const unsigned short* sp1 = Bth + (size_t)(n0 + lr) * K + g * 8;
  int s0 = w * 16;
  int s1 = (w + 4) * 16;

  f32x4 acc[4][4];
#pragma unroll
  for (int t = 0; t < 4; ++t)
#pragma unroll
    for (int u = 0; u < 4; ++u) acc[t][u] = (f32x4){0.f, 0.f, 0.f, 0.f};

  int sl8 = (quad ^ ((l16 >> 1) & 3)) * 8;

  int kend = z * 512 + 512;
  for (int k0 = z * 512; k0 < kend; k0 += 32) {
    __syncthreads();
    gload16(sp0 + (size_t)s0 * K + k0, &lds[0][s0][0]);
    gload16(sp0 + (size_t)s1 * K + k0, &lds[0][s1][0]);
    gload16(sp1 + (size_t)s0 * K + k0, &lds[1][s0][0]);
    gload16(sp1 + (size_t)s1 * K + k0, &lds[1][s1][0]);
    __syncthreads();

    short8 ah[4], bh[4];
#pragma unroll
    for (int t = 0; t < 4; ++t)
      ah[t] = *(const short8*)&lds[0][wm + t * 16 + l16][sl8];
#pragma unroll
    for (int u = 0; u < 4; ++u)
      bh[u] = *(const short8*)&lds[1][wn + u * 16 + l16][sl8];
#pragma unroll
    for (int t = 0; t < 4; ++t)
#pragma unroll
      for (int u = 0; u < 4; ++u)
        acc[t][u] = __builtin_amdgcn_mfma_f32_16x16x32_bf16(ah[t], bh[u], acc[t][u], 0, 0, 0);
  }

#pragma unroll
  for (int t = 0; t < 4; ++t) {
    int row = m0 + wm + t * 16 + quad * 4;
#pragma unroll
    for (int u = 0; u < 4; ++u) {
      int col = n0 + wn + u * 16 + l16;
      float bvv = (z == 0) ? bias[col] : 0.f;
#pragma unroll
      for (int i = 0; i < 4; ++i)
        atomicAdd(&C[(size_t)(row + i) * N + col], acc[t][u][i] + bvv);
    }
  }
}

// ---------------- fused RoPE + per-(b,s) head-attention ----------------
// bf16 q/k/v in, fp32 compute; attn fp32 out; ctx bf16 out (scrambled layout).
__global__ __launch_bounds__(256) void attn_rope_k(
    const unsigned short* __restrict__ q, const unsigned short* __restrict__ kk,
    const unsigned short* __restrict__ v,
    float* __restrict__ attn_out, unsigned short* __restrict__ ctx_h) {
  __shared__ float qs[16][68], ks[16][68], vs[16][68], as[16][17];
  int m = blockIdx.x;            // b*S + s
  int tid = threadIdx.x;
  int s = m & (SEQ - 1);
  size_t base4 = (size_t)m * (HD / 4);
  {
    int h = tid >> 4, dd = (tid & 15) * 4;
    us4 qv = ((const us4*)q)[base4 + tid];
    us4 kv = ((const us4*)kk)[base4 + tid];
    us4 vv = ((const us4*)v)[base4 + tid];
#pragma unroll
    for (int j = 0; j < 4; ++j) {
      qs[h][dd + j] = bf2f(qv[j]);
      ks[h][dd + j] = bf2f(kv[j]);
      vs[h][dd + j] = bf2f(vv[j]);
    }
  }
  __syncthreads();
  // RoPE: pairs (d, d+512) over flat hidden -> (h, dd) with (h+8, dd)
#pragma unroll
  for (int d = tid; d < 512; d += 256) {
    float f = exp2f(-(float)d * 0.025952563241307517f);  // log2(10000)/512
    float th = (float)s * f;
    float sv, cv;
    sincosf(th, &sv, &cv);      // accurate range reduction (th up to ~2047 rad)
    int h1 = d >> 6, dd = d & 63, h2 = h1 + 8;
    float q1 = qs[h1][dd], q2 = qs[h2][dd];
    qs[h1][dd] = q1 * cv - q2 * sv;
    qs[h2][dd] = q2 * cv + q1 * sv;
    float k1 = ks[h1][dd], k2 = ks[h2][dd];
    ks[h1][dd] = k1 * cv - k2 * sv;
    ks[h2][dd] = k2 * cv + k1 * sv;
  }
  __syncthreads();
  int h = tid >> 4, t = tid & 15;
  float sc = 0.f;
#pragma unroll
  for (int d = 0; d < 64; ++d) sc = fmaf(qs[h][d], ks[t][d], sc);
  sc *= 0.125f;   // 1/sqrt(64)
  float mx = sc;
  mx = fmaxf(mx, __shfl_xor(mx, 1));
  mx = fmaxf(mx, __shfl_xor(mx, 2));
  mx = fmaxf(mx, __shfl_xor(mx, 4));
  mx = fmaxf(mx, __shfl_xor(mx, 8));
  float e = expf(sc - mx);
  float sum = e;
  sum += __shfl_xor(sum, 1);
  sum += __shfl_xor(sum, 2);
  sum += __shfl_xor(sum, 4);
  sum += __shfl_xor(sum, 8);
  float a = e / sum;
  attn_out[(size_t)m * 256 + tid] = a;
  as[h][t] = a;
  __syncthreads();
  int b = m >> 11;
  for (int j = tid; j < 1024; j += 256) {
    int h2 = j >> 6, d = j & 63;
    float c = 0.f;
#pragma unroll
    for (int t2 = 0; t2 < 16; ++t2) c = fmaf(as[h2][t2], vs[t2][d], c);
    int row = b * SEQ + h2 * 128 + (s >> 4);
    int col = (s & 15) * 64 + d;
    ctx_h[(size_t)row * HD + col] = f2bf(c);
  }
}

extern "C" void kernel_launch(void* const* d_in, const int* in_sizes, int n_in,
                              void* d_out, int out_size, void* d_ws, size_t ws_size,
                              hipStream_t stream) {
  const float* inputs  = (const float*)d_in[0];
  const float* context = (const float*)d_in[1];
  const float* Wq = (const float*)d_in[2];
  const float* bq = (const float*)d_in[3];
  const float* Wk = (const float*)d_in[4];
  const float* bk = (const float*)d_in[5];
  const float* Wv = (const float*)d_in[6];
  const float* bv = (const float*)d_in[7];
  const float* Wo = (const float*)d_in[8];
  const float* bo = (const float*)d_in[9];

  float* out  = (float*)d_out;                     // [2,2048,1024] flat
  float* attn = out + (size_t)4096 * 1024;         // [2,2048,16,16] flat

  // ws layout (MB offsets), all bf16 planes 8 MB except wt (4 x 2 MB):
  // q=0, k=8, v=16, wt=24..32, Ih=32..40, Ch=40..48; ctxh aliases Ih (dead
  // after gemm_qkv; attn and gemm_o are later dispatches -> no intra-dispatch
  // aliasing anywhere).
  const size_t MB = 1ull << 20;
  char* wsb = (char*)d_ws;
  unsigned short* q  = (unsigned short*)(wsb + 0 * MB);
  unsigned short* k  = (unsigned short*)(wsb + 8 * MB);
  unsigned short* v  = (unsigned short*)(wsb + 16 * MB);
  unsigned short* wt = (unsigned short*)(wsb + 24 * MB);
  unsigned short* Ih = (unsigned short*)(wsb + 32 * MB);
  unsigned short* Ch = (unsigned short*)(wsb + 40 * MB);
  unsigned short* ctxh = Ih;   // alias, cross-dispatch only

  prep<<<9216, 256, 0, stream>>>(inputs, context, Wq, Wk, Wv, Wo, Ih, Ch, wt, out);

  gemm_qkv<<<dim3(32, 8, 3), 256, 0, stream>>>(Ih, Ch, wt, bq, bk, bv, q, k, v);

  attn_rope_k<<<4096, 256, 0, stream>>>(q, k, v, attn, ctxh);

  const size_t P = (size_t)1024 * 1024;
  gemm_o_splitk<<<dim3(32, 8, 2), 256, 0, stream>>>(ctxh, wt + 3 * P, bo, out);
}

// Round 7
// 189.356 us; speedup vs baseline: 1.6834x; 1.0046x over previous
//
#include <hip/hip_runtime.h>
#include <hip/hip_bf16.h>
#include <cstdint>

typedef __attribute__((ext_vector_type(8))) short short8;
typedef __attribute__((ext_vector_type(4))) float f32x4;
typedef __attribute__((ext_vector_type(2))) float f32x2;
typedef __attribute__((ext_vector_type(4))) float float4v;
typedef __attribute__((ext_vector_type(4))) unsigned short us4;

#define HD 1024
#define SEQ 2048

// fp32 -> bf16 (round-to-nearest-even), raw bits; inputs are finite.
__device__ __forceinline__ unsigned short f2bf(float f) {
  uint32_t u = __builtin_bit_cast(uint32_t, f);
  return (unsigned short)((u + 0x7FFFu + ((u >> 16) & 1u)) >> 16);
}
__device__ __forceinline__ float bf2f(unsigned short s) {
  return __builtin_bit_cast(float, (uint32_t)s << 16);
}

// async global->LDS, 16B per lane, dest = wave-uniform base + lane*16
__device__ __forceinline__ void gload16(const unsigned short* g, unsigned short* l) {
  __builtin_amdgcn_global_load_lds(
      (const __attribute__((address_space(1))) void*)g,
      (__attribute__((address_space(3))) void*)l, 16, 0, 0);
}

// ---------------- fused prep ----------------
// bx [0,4096):     bf16 cast of inputs (bx<2048) / context
// bx [4096,8192):  transpose + bf16 cast of weight (bx-4096)>>10
// bx [8192,9216):  zero d_out's `out` region (16 MB)
// bx [9216,10240): RoPE cos/sin table, 2048 x 512 float2
__global__ __launch_bounds__(256) void prep(
    const float* __restrict__ X, const float* __restrict__ Y,
    const float* __restrict__ w0, const float* __restrict__ w1,
    const float* __restrict__ w2, const float* __restrict__ w3,
    unsigned short* __restrict__ Xh, unsigned short* __restrict__ Yh,
    unsigned short* __restrict__ wt, float* __restrict__ outz,
    f32x2* __restrict__ tab) {
  __shared__ float tile[32][33];
  int bx = blockIdx.x;
  int tid = threadIdx.x;
  if (bx < 4096) {
    const float* src = (bx >= 2048) ? Y : X;
    unsigned short* oh = (bx >= 2048) ? Yh : Xh;
    int i0 = (bx & 2047) * 512 + tid;
#pragma unroll
    for (int r = 0; r < 2; ++r) {
      int i = i0 + r * 256;
      float4v v = ((const float4v*)src)[i];
      us4 h;
#pragma unroll
      for (int j = 0; j < 4; ++j) h[j] = f2bf(v[j]);
      ((us4*)oh)[i] = h;
    }
  } else if (bx < 8192) {
    int t = bx - 4096;
    int z = t >> 10;
    int rem = t & 1023;
    int bxx = rem & 31, byy = rem >> 5;
    const float* in = (z == 0) ? w0 : (z == 1) ? w1 : (z == 2) ? w2 : w3;
    unsigned short* oh = wt + (size_t)z * 1024 * 1024;
    int tx = tid & 31, ty = tid >> 5;
    int x = bxx * 32 + tx;
    int y0 = byy * 32;
    for (int i = ty; i < 32; i += 8)
      tile[i][tx] = in[(size_t)(y0 + i) * HD + x];
    __syncthreads();
    int x2 = y0 + tx;               // k index after transpose
    int y2 = bxx * 32;              // n index after transpose
    for (int i = ty; i < 32; i += 8)
      oh[(size_t)(y2 + i) * HD + x2] = f2bf(tile[tx][i]);
  } else if (bx < 9216) {
    int i0 = (bx - 8192) * 1024 + tid;
    float4v zv = {0.f, 0.f, 0.f, 0.f};
#pragma unroll
    for (int r = 0; r < 4; ++r)
      ((float4v*)outz)[i0 + r * 256] = zv;
  } else {
    int e0 = (bx - 9216) * 1024 + tid;
#pragma unroll
    for (int r = 0; r < 4; ++r) {
      int e = e0 + r * 256;        // e = s*512 + d, e < 1M
      int s = e >> 9, d = e & 511;
      float f = exp2f(-(float)d * 0.025952563241307517f);  // log2(10000)/512
      float th = (float)s * f;
      float sv, cv;
      sincosf(th, &sv, &cv);
      f32x2 cs; cs[0] = cv; cs[1] = sv;
      tab[e] = cs;
    }
  }
}

// ---------------- batched QKV GEMM, pure bf16, BK=64 ----------------
// z=0: q = inputs@Wq+bq ; z=1: k = context@Wk+bk ; z=2: v = context@Wv+bv.
// 128x128 tile, 256 thr = 4 waves (2m x 2n), wave tile 64x64.
// LDS: 2 planes [128][64], XOR-swizzled 8-chunk rows (slot c of row r holds
// global chunk c ^ ((r>>1)&7)); seg parity folds into two per-lane src ptrs.
// 16 barrier pairs instead of 32 (BK=64 amortizes the vmcnt(0) drain).
__global__ __launch_bounds__(256, 3) void gemm_qkv(
    const unsigned short* __restrict__ Ih, const unsigned short* __restrict__ Ch,
    const unsigned short* __restrict__ wt,
    const float* __restrict__ bq, const float* __restrict__ bk, const float* __restrict__ bv,
    unsigned short* __restrict__ qo, unsigned short* __restrict__ ko,
    unsigned short* __restrict__ vo) {
  __shared__ __align__(16) unsigned short lds[2][128][64];
  const int K = HD, N = HD;
  const size_t P = (size_t)1024 * 1024;
  int z  = blockIdx.z;
  const unsigned short* Ah = z ? Ch : Ih;
  const unsigned short* Bth = wt + (size_t)z * P;
  const float* bias = (z == 0) ? bq : (z == 1) ? bk : bv;
  unsigned short* C = (z == 0) ? qo : (z == 1) ? ko : vo;

  int m0 = blockIdx.x * 128;
  int n0 = blockIdx.y * 128;
  int tid  = threadIdx.x;
  int lane = tid & 63;
  int w    = tid >> 6;            // 0..3
  int quad = lane >> 4;
  int l16  = lane & 15;
  int wm = (w >> 1) * 64;
  int wn = (w & 1) * 64;

  // staging: seg in [0,16), 8 rows each; lane: ro=lane>>3 row-in-seg, sl=lane&7 slot
  int ro = lane >> 3;
  int sl = lane & 7;
  int ge = sl ^ (ro >> 1);        // even-seg global chunk
  int go = ge ^ 4;                // odd-seg
  const unsigned short* spA_e = Ah  + (size_t)(m0 + ro) * K + ge * 8;
  const unsigned short* spA_o = Ah  + (size_t)(m0 + ro) * K + go * 8;
  const unsigned short* spB_e = Bth + (size_t)(n0 + ro) * K + ge * 8;
  const unsigned short* spB_o = Bth + (size_t)(n0 + ro) * K + go * 8;

  f32x4 acc[4][4];
#pragma unroll
  for (int t = 0; t < 4; ++t)
#pragma unroll
    for (int u = 0; u < 4; ++u) acc[t][u] = (f32x4){0.f, 0.f, 0.f, 0.f};

  for (int k0 = 0; k0 < K; k0 += 64) {
    __syncthreads();
#pragma unroll
    for (int i = 0; i < 4; ++i) {
      int seg = w + i * 4;
      const unsigned short* pa = (seg & 1) ? spA_o : spA_e;
      const unsigned short* pb = (seg & 1) ? spB_o : spB_e;
      gload16(pa + (size_t)seg * 8 * K + k0, &lds[0][seg * 8][0]);
      gload16(pb + (size_t)seg * 8 * K + k0, &lds[1][seg * 8][0]);
    }
    __syncthreads();

#pragma unroll
    for (int j = 0; j < 2; ++j) {
      int sl8 = (((j << 2) | quad) ^ (l16 >> 1)) * 8;
      short8 ah[4], bh[4];
#pragma unroll
      for (int t = 0; t < 4; ++t)
        ah[t] = *(const short8*)&lds[0][wm + t * 16 + l16][sl8];
#pragma unroll
      for (int u = 0; u < 4; ++u)
        bh[u] = *(const short8*)&lds[1][wn + u * 16 + l16][sl8];
#pragma unroll
      for (int t = 0; t < 4; ++t)
#pragma unroll
        for (int u = 0; u < 4; ++u)
          acc[t][u] = __builtin_amdgcn_mfma_f32_16x16x32_bf16(ah[t], bh[u], acc[t][u], 0, 0, 0);
    }
  }

#pragma unroll
  for (int t = 0; t < 4; ++t) {
    int row = m0 + wm + t * 16 + quad * 4;
#pragma unroll
    for (int u = 0; u < 4; ++u) {
      int col = n0 + wn + u * 16 + l16;
      float bvv = bias[col];
#pragma unroll
      for (int i = 0; i < 4; ++i)
        C[(size_t)(row + i) * N + col] = f2bf(acc[t][u][i] + bvv);
    }
  }
}

// ---------------- O GEMM, pure bf16, BK=64, split-K=2, atomic epilogue ----------
// z in {0,1}: K-range [z*512, z*512+512). out pre-zeroed; z==0 adds bias.
__global__ __launch_bounds__(256, 3) void gemm_o_splitk(
    const unsigned short* __restrict__ Ah, const unsigned short* __restrict__ Bth,
    const float* __restrict__ bias, float* __restrict__ C) {
  __shared__ __align__(16) unsigned short lds[2][128][64];
  const int K = HD, N = HD;
  int z  = blockIdx.z;
  int m0 = blockIdx.x * 128;
  int n0 = blockIdx.y * 128;
  int tid  = threadIdx.x;
  int lane = tid & 63;
  int w    = tid >> 6;
  int quad = lane >> 4;
  int l16  = lane & 15;
  int wm = (w >> 1) * 64;
  int wn = (w & 1) * 64;

  int ro = lane >> 3;
  int sl = lane & 7;
  int ge = sl ^ (ro >> 1);
  int go = ge ^ 4;
  const unsigned short* spA_e = Ah  + (size_t)(m0 + ro) * K + ge * 8;
  const unsigned short* spA_o = Ah  + (size_t)(m0 + ro) * K + go * 8;
  const unsigned short* spB_e = Bth + (size_t)(n0 + ro) * K + ge * 8;
  const unsigned short* spB_o = Bth + (size_t)(n0 + ro) * K + go * 8;

  f32x4 acc[4][4];
#pragma unroll
  for (int t = 0; t < 4; ++t)
#pragma unroll
    for (int u = 0; u < 4; ++u) acc[t][u] = (f32x4){0.f, 0.f, 0.f, 0.f};

  int kend = z * 512 + 512;
  for (int k0 = z * 512; k0 < kend; k0 += 64) {
    __syncthreads();
#pragma unroll
    for (int i = 0; i < 4; ++i) {
      int seg = w + i * 4;
      const unsigned short* pa = (seg & 1) ? spA_o : spA_e;
      const unsigned short* pb = (seg & 1) ? spB_o : spB_e;
      gload16(pa + (size_t)seg * 8 * K + k0, &lds[0][seg * 8][0]);
      gload16(pb + (size_t)seg * 8 * K + k0, &lds[1][seg * 8][0]);
    }
    __syncthreads();

#pragma unroll
    for (int j = 0; j < 2; ++j) {
      int sl8 = (((j << 2) | quad) ^ (l16 >> 1)) * 8;
      short8 ah[4], bh[4];
#pragma unroll
      for (int t = 0; t < 4; ++t)
        ah[t] = *(const short8*)&lds[0][wm + t * 16 + l16][sl8];
#pragma unroll
      for (int u = 0; u < 4; ++u)
        bh[u] = *(const short8*)&lds[1][wn + u * 16 + l16][sl8];
#pragma unroll
      for (int t = 0; t < 4; ++t)
#pragma unroll
        for (int u = 0; u < 4; ++u)
          acc[t][u] = __builtin_amdgcn_mfma_f32_16x16x32_bf16(ah[t], bh[u], acc[t][u], 0, 0, 0);
    }
  }

#pragma unroll
  for (int t = 0; t < 4; ++t) {
    int row = m0 + wm + t * 16 + quad * 4;
#pragma unroll
    for (int u = 0; u < 4; ++u) {
      int col = n0 + wn + u * 16 + l16;
      float bvv = (z == 0) ? bias[col] : 0.f;
#pragma unroll
      for (int i = 0; i < 4; ++i)
        atomicAdd(&C[(size_t)(row + i) * N + col], acc[t][u][i] + bvv);
    }
  }
}

// ---------------- fused RoPE + per-(b,s) head-attention ----------------
// bf16 q/k/v in, fp32 compute; cos/sin from precomputed table; attn fp32 out;
// ctx bf16 out in the transpose(0,2,1,3) scrambled layout.
__global__ __launch_bounds__(256) void attn_rope_k(
    const unsigned short* __restrict__ q, const unsigned short* __restrict__ kk,
    const unsigned short* __restrict__ v, const f32x2* __restrict__ tab,
    float* __restrict__ attn_out, unsigned short* __restrict__ ctx_h) {
  __shared__ float qs[16][68], ks[16][68], vs[16][68], as[16][17];
  int m = blockIdx.x;            // b*S + s
  int tid = threadIdx.x;
  int s = m & (SEQ - 1);
  size_t base4 = (size_t)m * (HD / 4);
  {
    int h = tid >> 4, dd = (tid & 15) * 4;
    us4 qv = ((const us4*)q)[base4 + tid];
    us4 kv = ((const us4*)kk)[base4 + tid];
    us4 vv = ((const us4*)v)[base4 + tid];
#pragma unroll
    for (int j = 0; j < 4; ++j) {
      qs[h][dd + j] = bf2f(qv[j]);
      ks[h][dd + j] = bf2f(kv[j]);
      vs[h][dd + j] = bf2f(vv[j]);
    }
  }
  __syncthreads();
  // RoPE: pairs (d, d+512) over flat hidden -> (h, dd) with (h+8, dd)
#pragma unroll
  for (int d = tid; d < 512; d += 256) {
    f32x2 cs = tab[(s << 9) + d];
    float cv = cs[0], sv = cs[1];
    int h1 = d >> 6, dd = d & 63, h2 = h1 + 8;
    float q1 = qs[h1][dd], q2 = qs[h2][dd];
    qs[h1][dd] = q1 * cv - q2 * sv;
    qs[h2][dd] = q2 * cv + q1 * sv;
    float k1 = ks[h1][dd], k2 = ks[h2][dd];
    ks[h1][dd] = k1 * cv - k2 * sv;
    ks[h2][dd] = k2 * cv + k1 * sv;
  }
  __syncthreads();
  int h = tid >> 4, t = tid & 15;
  float sc = 0.f;
#pragma unroll
  for (int d = 0; d < 64; ++d) sc = fmaf(qs[h][d], ks[t][d], sc);
  sc *= 0.125f;   // 1/sqrt(64)
  float mx = sc;
  mx = fmaxf(mx, __shfl_xor(mx, 1));
  mx = fmaxf(mx, __shfl_xor(mx, 2));
  mx = fmaxf(mx, __shfl_xor(mx, 4));
  mx = fmaxf(mx, __shfl_xor(mx, 8));
  float e = expf(sc - mx);
  float sum = e;
  sum += __shfl_xor(sum, 1);
  sum += __shfl_xor(sum, 2);
  sum += __shfl_xor(sum, 4);
  sum += __shfl_xor(sum, 8);
  float a = e / sum;
  attn_out[(size_t)m * 256 + tid] = a;
  as[h][t] = a;
  __syncthreads();
  int b = m >> 11;
  for (int j = tid; j < 1024; j += 256) {
    int h2 = j >> 6, d = j & 63;
    float c = 0.f;
#pragma unroll
    for (int t2 = 0; t2 < 16; ++t2) c = fmaf(as[h2][t2], vs[t2][d], c);
    int row = b * SEQ + h2 * 128 + (s >> 4);
    int col = (s & 15) * 64 + d;
    ctx_h[(size_t)row * HD + col] = f2bf(c);
  }
}

extern "C" void kernel_launch(void* const* d_in, const int* in_sizes, int n_in,
                              void* d_out, int out_size, void* d_ws, size_t ws_size,
                              hipStream_t stream) {
  const float* inputs  = (const float*)d_in[0];
  const float* context = (const float*)d_in[1];
  const float* Wq = (const float*)d_in[2];
  const float* bq = (const float*)d_in[3];
  const float* Wk = (const float*)d_in[4];
  const float* bk = (const float*)d_in[5];
  const float* Wv = (const float*)d_in[6];
  const float* bv = (const float*)d_in[7];
  const float* Wo = (const float*)d_in[8];
  const float* bo = (const float*)d_in[9];

  float* out  = (float*)d_out;                     // [2,2048,1024] flat
  float* attn = out + (size_t)4096 * 1024;         // [2,2048,16,16] flat

  // ws layout (MB offsets): q=0, k=8, v=16, wt=24..32, Ih=32..40, Ch=40..48,
  // tab=48..56. ctxh aliases Ih (dead after gemm_qkv; cross-dispatch only).
  const size_t MB = 1ull << 20;
  char* wsb = (char*)d_ws;
  unsigned short* q  = (unsigned short*)(wsb + 0 * MB);
  unsigned short* k  = (unsigned short*)(wsb + 8 * MB);
  unsigned short* v  = (unsigned short*)(wsb + 16 * MB);
  unsigned short* wt = (unsigned short*)(wsb + 24 * MB);
  unsigned short* Ih = (unsigned short*)(wsb + 32 * MB);
  unsigned short* Ch = (unsigned short*)(wsb + 40 * MB);
  f32x2* tab = (f32x2*)(wsb + 48 * MB);
  unsigned short* ctxh = Ih;   // alias, cross-dispatch only

  prep<<<10240, 256, 0, stream>>>(inputs, context, Wq, Wk, Wv, Wo,
                                  Ih, Ch, wt, out, tab);

  gemm_qkv<<<dim3(32, 8, 3), 256, 0, stream>>>(Ih, Ch, wt, bq, bk, bv, q, k, v);

  attn_rope_k<<<4096, 256, 0, stream>>>(q, k, v, tab, attn, ctxh);

  const size_t P = (size_t)1024 * 1024;
  gemm_o_splitk<<<dim3(32, 8, 2), 256, 0, stream>>>(ctxh, wt + 3 * P, bo, out);
}

// Round 8
// 170.854 us; speedup vs baseline: 1.8657x; 1.1083x over previous
//
#include <hip/hip_runtime.h>
#include <hip/hip_bf16.h>
#include <cstdint>

typedef __attribute__((ext_vector_type(8))) short short8;
typedef __attribute__((ext_vector_type(4))) float f32x4;
typedef __attribute__((ext_vector_type(2))) float f32x2;
typedef __attribute__((ext_vector_type(4))) float float4v;
typedef __attribute__((ext_vector_type(4))) unsigned short us4;

#define HD 1024
#define SEQ 2048

// fp32 -> bf16 (round-to-nearest-even), raw bits; inputs are finite.
__device__ __forceinline__ unsigned short f2bf(float f) {
  uint32_t u = __builtin_bit_cast(uint32_t, f);
  return (unsigned short)((u + 0x7FFFu + ((u >> 16) & 1u)) >> 16);
}
__device__ __forceinline__ float bf2f(unsigned short s) {
  return __builtin_bit_cast(float, (uint32_t)s << 16);
}

// async global->LDS, 16B per lane, dest = wave-uniform base + lane*16
__device__ __forceinline__ void gload16(const unsigned short* g, unsigned short* l) {
  __builtin_amdgcn_global_load_lds(
      (const __attribute__((address_space(1))) void*)g,
      (__attribute__((address_space(3))) void*)l, 16, 0, 0);
}

// ---------------- fused prep ----------------
// bx [0,4096):    bf16 cast of inputs (bx<2048) / context
// bx [4096,8192): transpose + bf16 cast of weight (bx-4096)>>10
// bx [8192,9216): RoPE cos/sin table, 2048 x 512 float2
__global__ __launch_bounds__(256) void prep(
    const float* __restrict__ X, const float* __restrict__ Y,
    const float* __restrict__ w0, const float* __restrict__ w1,
    const float* __restrict__ w2, const float* __restrict__ w3,
    unsigned short* __restrict__ Xh, unsigned short* __restrict__ Yh,
    unsigned short* __restrict__ wt, f32x2* __restrict__ tab) {
  __shared__ float tile[32][33];
  int bx = blockIdx.x;
  int tid = threadIdx.x;
  if (bx < 4096) {
    const float* src = (bx >= 2048) ? Y : X;
    unsigned short* oh = (bx >= 2048) ? Yh : Xh;
    int i0 = (bx & 2047) * 512 + tid;
#pragma unroll
    for (int r = 0; r < 2; ++r) {
      int i = i0 + r * 256;
      float4v v = ((const float4v*)src)[i];
      us4 h;
#pragma unroll
      for (int j = 0; j < 4; ++j) h[j] = f2bf(v[j]);
      ((us4*)oh)[i] = h;
    }
  } else if (bx < 8192) {
    int t = bx - 4096;
    int z = t >> 10;
    int rem = t & 1023;
    int bxx = rem & 31, byy = rem >> 5;
    const float* in = (z == 0) ? w0 : (z == 1) ? w1 : (z == 2) ? w2 : w3;
    unsigned short* oh = wt + (size_t)z * 1024 * 1024;
    int tx = tid & 31, ty = tid >> 5;
    int x = bxx * 32 + tx;
    int y0 = byy * 32;
    for (int i = ty; i < 32; i += 8)
      tile[i][tx] = in[(size_t)(y0 + i) * HD + x];
    __syncthreads();
    int x2 = y0 + tx;               // k index after transpose
    int y2 = bxx * 32;              // n index after transpose
    for (int i = ty; i < 32; i += 8)
      oh[(size_t)(y2 + i) * HD + x2] = f2bf(tile[tx][i]);
  } else {
    int e0 = (bx - 8192) * 1024 + tid;
#pragma unroll
    for (int r = 0; r < 4; ++r) {
      int e = e0 + r * 256;        // e = s*512 + d, e < 1M
      int s = e >> 9, d = e & 511;
      float f = exp2f(-(float)d * 0.025952563241307517f);  // log2(10000)/512
      float th = (float)s * f;
      float sv, cv;
      sincosf(th, &sv, &cv);
      f32x2 cs; cs[0] = cv; cs[1] = sv;
      tab[e] = cs;
    }
  }
}

// ---------------- batched QKV GEMM, pure bf16, BK=64 ----------------
// z=0: q = inputs@Wq+bq ; z=1: k = context@Wk+bk ; z=2: v = context@Wv+bv.
// 128x128 tile, 256 thr = 4 waves (2m x 2n), wave tile 64x64.
// LDS: 2 planes [128][64], XOR-swizzled 8-chunk rows (slot c of row r holds
// global chunk c ^ ((r>>1)&7)); seg parity folds into two per-lane src ptrs.
__global__ __launch_bounds__(256, 3) void gemm_qkv(
    const unsigned short* __restrict__ Ih, const unsigned short* __restrict__ Ch,
    const unsigned short* __restrict__ wt,
    const float* __restrict__ bq, const float* __restrict__ bk, const float* __restrict__ bv,
    unsigned short* __restrict__ qo, unsigned short* __restrict__ ko,
    unsigned short* __restrict__ vo) {
  __shared__ __align__(16) unsigned short lds[2][128][64];
  const int K = HD, N = HD;
  const size_t P = (size_t)1024 * 1024;
  int z  = blockIdx.z;
  const unsigned short* Ah = z ? Ch : Ih;
  const unsigned short* Bth = wt + (size_t)z * P;
  const float* bias = (z == 0) ? bq : (z == 1) ? bk : bv;
  unsigned short* C = (z == 0) ? qo : (z == 1) ? ko : vo;

  int m0 = blockIdx.x * 128;
  int n0 = blockIdx.y * 128;
  int tid  = threadIdx.x;
  int lane = tid & 63;
  int w    = tid >> 6;            // 0..3
  int quad = lane >> 4;
  int l16  = lane & 15;
  int wm = (w >> 1) * 64;
  int wn = (w & 1) * 64;

  int ro = lane >> 3;             // 0..7 row-in-seg
  int sl = lane & 7;              // slot
  int ge = sl ^ (ro >> 1);        // even-seg global chunk
  int go = ge ^ 4;                // odd-seg
  const unsigned short* spA_e = Ah  + (size_t)(m0 + ro) * K + ge * 8;
  const unsigned short* spA_o = Ah  + (size_t)(m0 + ro) * K + go * 8;
  const unsigned short* spB_e = Bth + (size_t)(n0 + ro) * K + ge * 8;
  const unsigned short* spB_o = Bth + (size_t)(n0 + ro) * K + go * 8;

  f32x4 acc[4][4];
#pragma unroll
  for (int t = 0; t < 4; ++t)
#pragma unroll
    for (int u = 0; u < 4; ++u) acc[t][u] = (f32x4){0.f, 0.f, 0.f, 0.f};

  for (int k0 = 0; k0 < K; k0 += 64) {
    __syncthreads();
#pragma unroll
    for (int i = 0; i < 4; ++i) {
      int seg = w + i * 4;
      const unsigned short* pa = (seg & 1) ? spA_o : spA_e;
      const unsigned short* pb = (seg & 1) ? spB_o : spB_e;
      gload16(pa + (size_t)seg * 8 * K + k0, &lds[0][seg * 8][0]);
      gload16(pb + (size_t)seg * 8 * K + k0, &lds[1][seg * 8][0]);
    }
    __syncthreads();

#pragma unroll
    for (int j = 0; j < 2; ++j) {
      int sl8 = (((j << 2) | quad) ^ (l16 >> 1)) * 8;
      short8 ah[4], bh[4];
#pragma unroll
      for (int t = 0; t < 4; ++t)
        ah[t] = *(const short8*)&lds[0][wm + t * 16 + l16][sl8];
#pragma unroll
      for (int u = 0; u < 4; ++u)
        bh[u] = *(const short8*)&lds[1][wn + u * 16 + l16][sl8];
#pragma unroll
      for (int t = 0; t < 4; ++t)
#pragma unroll
        for (int u = 0; u < 4; ++u)
          acc[t][u] = __builtin_amdgcn_mfma_f32_16x16x32_bf16(ah[t], bh[u], acc[t][u], 0, 0, 0);
    }
  }

#pragma unroll
  for (int t = 0; t < 4; ++t) {
    int row = m0 + wm + t * 16 + quad * 4;
#pragma unroll
    for (int u = 0; u < 4; ++u) {
      int col = n0 + wn + u * 16 + l16;
      float bvv = bias[col];
#pragma unroll
      for (int i = 0; i < 4; ++i)
        C[(size_t)(row + i) * N + col] = f2bf(acc[t][u][i] + bvv);
    }
  }
}

// ---------------- O GEMM, pure bf16, 128x64 tile, direct write ----------------
// grid (32,16) = 512 blocks (2/CU). Full K per block -> no atomics, no zero-fill.
// 4 waves (2m x 2n), wave tile 64x32 (4x2 accs). LDS A[128][64] + B[64][64].
__global__ __launch_bounds__(256, 3) void gemm_o(
    const unsigned short* __restrict__ Ah, const unsigned short* __restrict__ Bth,
    const float* __restrict__ bias, float* __restrict__ C) {
  __shared__ __align__(16) unsigned short ldsA[128][64];
  __shared__ __align__(16) unsigned short ldsB[64][64];
  const int K = HD, N = HD;
  int m0 = blockIdx.x * 128;
  int n0 = blockIdx.y * 64;
  int tid  = threadIdx.x;
  int lane = tid & 63;
  int w    = tid >> 6;            // 0..3
  int quad = lane >> 4;
  int l16  = lane & 15;
  int wm = (w >> 1) * 64;         // 0/64
  int wn = (w & 1) * 32;          // 0/32

  int ro = lane >> 3;
  int sl = lane & 7;
  int ge = sl ^ (ro >> 1);
  int go = ge ^ 4;
  const unsigned short* spA_e = Ah  + (size_t)(m0 + ro) * K + ge * 8;
  const unsigned short* spA_o = Ah  + (size_t)(m0 + ro) * K + go * 8;
  const unsigned short* spB_e = Bth + (size_t)(n0 + ro) * K + ge * 8;
  const unsigned short* spB_o = Bth + (size_t)(n0 + ro) * K + go * 8;

  f32x4 acc[4][2];
#pragma unroll
  for (int t = 0; t < 4; ++t)
#pragma unroll
    for (int u = 0; u < 2; ++u) acc[t][u] = (f32x4){0.f, 0.f, 0.f, 0.f};

  for (int k0 = 0; k0 < K; k0 += 64) {
    __syncthreads();
#pragma unroll
    for (int i = 0; i < 4; ++i) {          // A segs: w, w+4, w+8, w+12
      int seg = w + i * 4;
      const unsigned short* pa = (seg & 1) ? spA_o : spA_e;
      gload16(pa + (size_t)seg * 8 * K + k0, &ldsA[seg * 8][0]);
    }
#pragma unroll
    for (int i = 0; i < 2; ++i) {          // B segs: w, w+4
      int seg = w + i * 4;
      const unsigned short* pb = (seg & 1) ? spB_o : spB_e;
      gload16(pb + (size_t)seg * 8 * K + k0, &ldsB[seg * 8][0]);
    }
    __syncthreads();

#pragma unroll
    for (int j = 0; j < 2; ++j) {
      int sl8 = (((j << 2) | quad) ^ (l16 >> 1)) * 8;
      short8 ah[4], bh[2];
#pragma unroll
      for (int t = 0; t < 4; ++t)
        ah[t] = *(const short8*)&ldsA[wm + t * 16 + l16][sl8];
#pragma unroll
      for (int u = 0; u < 2; ++u)
        bh[u] = *(const short8*)&ldsB[wn + u * 16 + l16][sl8];
#pragma unroll
      for (int t = 0; t < 4; ++t)
#pragma unroll
        for (int u = 0; u < 2; ++u)
          acc[t][u] = __builtin_amdgcn_mfma_f32_16x16x32_bf16(ah[t], bh[u], acc[t][u], 0, 0, 0);
    }
  }

#pragma unroll
  for (int t = 0; t < 4; ++t) {
    int row = m0 + wm + t * 16 + quad * 4;
#pragma unroll
    for (int u = 0; u < 2; ++u) {
      int col = n0 + wn + u * 16 + l16;
      float bvv = bias[col];
#pragma unroll
      for (int i = 0; i < 4; ++i)
        C[(size_t)(row + i) * N + col] = acc[t][u][i] + bvv;
    }
  }
}

// ---------------- fused RoPE + per-(b,s) head-attention ----------------
// bf16 q/k/v in, fp32 compute; cos/sin from precomputed table; attn fp32 out;
// ctx bf16 out in the transpose(0,2,1,3) scrambled layout.
__global__ __launch_bounds__(256) void attn_rope_k(
    const unsigned short* __restrict__ q, const unsigned short* __restrict__ kk,
    const unsigned short* __restrict__ v, const f32x2* __restrict__ tab,
    float* __restrict__ attn_out, unsigned short* __restrict__ ctx_h) {
  __shared__ float qs[16][68], ks[16][68], vs[16][68], as[16][17];
  int m = blockIdx.x;            // b*S + s
  int tid = threadIdx.x;
  int s = m & (SEQ - 1);
  size_t base4 = (size_t)m * (HD / 4);
  {
    int h = tid >> 4, dd = (tid & 15) * 4;
    us4 qv = ((const us4*)q)[base4 + tid];
    us4 kv = ((const us4*)kk)[base4 + tid];
    us4 vv = ((const us4*)v)[base4 + tid];
#pragma unroll
    for (int j = 0; j < 4; ++j) {
      qs[h][dd + j] = bf2f(qv[j]);
      ks[h][dd + j] = bf2f(kv[j]);
      vs[h][dd + j] = bf2f(vv[j]);
    }
  }
  __syncthreads();
  // RoPE: pairs (d, d+512) over flat hidden -> (h, dd) with (h+8, dd)
#pragma unroll
  for (int d = tid; d < 512; d += 256) {
    f32x2 cs = tab[(s << 9) + d];
    float cv = cs[0], sv = cs[1];
    int h1 = d >> 6, dd = d & 63, h2 = h1 + 8;
    float q1 = qs[h1][dd], q2 = qs[h2][dd];
    qs[h1][dd] = q1 * cv - q2 * sv;
    qs[h2][dd] = q2 * cv + q1 * sv;
    float k1 = ks[h1][dd], k2 = ks[h2][dd];
    ks[h1][dd] = k1 * cv - k2 * sv;
    ks[h2][dd] = k2 * cv + k1 * sv;
  }
  __syncthreads();
  int h = tid >> 4, t = tid & 15;
  float sc = 0.f;
#pragma unroll
  for (int d = 0; d < 64; ++d) sc = fmaf(qs[h][d], ks[t][d], sc);
  sc *= 0.125f;   // 1/sqrt(64)
  float mx = sc;
  mx = fmaxf(mx, __shfl_xor(mx, 1));
  mx = fmaxf(mx, __shfl_xor(mx, 2));
  mx = fmaxf(mx, __shfl_xor(mx, 4));
  mx = fmaxf(mx, __shfl_xor(mx, 8));
  float e = expf(sc - mx);
  float sum = e;
  sum += __shfl_xor(sum, 1);
  sum += __shfl_xor(sum, 2);
  sum += __shfl_xor(sum, 4);
  sum += __shfl_xor(sum, 8);
  float a = e / sum;
  attn_out[(size_t)m * 256 + tid] = a;
  as[h][t] = a;
  __syncthreads();
  int b = m >> 11;
  for (int j = tid; j < 1024; j += 256) {
    int h2 = j >> 6, d = j & 63;
    float c = 0.f;
#pragma unroll
    for (int t2 = 0; t2 < 16; ++t2) c = fmaf(as[h2][t2], vs[t2][d], c);
    int row = b * SEQ + h2 * 128 + (s >> 4);
    int col = (s & 15) * 64 + d;
    ctx_h[(size_t)row * HD + col] = f2bf(c);
  }
}

extern "C" void kernel_launch(void* const* d_in, const int* in_sizes, int n_in,
                              void* d_out, int out_size, void* d_ws, size_t ws_size,
                              hipStream_t stream) {
  const float* inputs  = (const float*)d_in[0];
  const float* context = (const float*)d_in[1];
  const float* Wq = (const float*)d_in[2];
  const float* bq = (const float*)d_in[3];
  const float* Wk = (const float*)d_in[4];
  const float* bk = (const float*)d_in[5];
  const float* Wv = (const float*)d_in[6];
  const float* bv = (const float*)d_in[7];
  const float* Wo = (const float*)d_in[8];
  const float* bo = (const float*)d_in[9];

  float* out  = (float*)d_out;                     // [2,2048,1024] flat
  float* attn = out + (size_t)4096 * 1024;         // [2,2048,16,16] flat

  // ws layout (MB offsets): q=0, k=8, v=16, wt=24..32, Ih=32..40, Ch=40..48,
  // tab=48..56. ctxh aliases Ih (dead after gemm_qkv; cross-dispatch only).
  const size_t MB = 1ull << 20;
  char* wsb = (char*)d_ws;
  unsigned short* q  = (unsigned short*)(wsb + 0 * MB);
  unsigned short* k  = (unsigned short*)(wsb + 8 * MB);
  unsigned short* v  = (unsigned short*)(wsb + 16 * MB);
  unsigned short* wt = (unsigned short*)(wsb + 24 * MB);
  unsigned short* Ih = (unsigned short*)(wsb + 32 * MB);
  unsigned short* Ch = (unsigned short*)(wsb + 40 * MB);
  f32x2* tab = (f32x2*)(wsb + 48 * MB);
  unsigned short* ctxh = Ih;   // alias, cross-dispatch only

  prep<<<9216, 256, 0, stream>>>(inputs, context, Wq, Wk, Wv, Wo, Ih, Ch, wt, tab);

  gemm_qkv<<<dim3(32, 8, 3), 256, 0, stream>>>(Ih, Ch, wt, bq, bk, bv, q, k, v);

  attn_rope_k<<<4096, 256, 0, stream>>>(q, k, v, tab, attn, ctxh);

  const size_t P = (size_t)1024 * 1024;
  gemm_o<<<dim3(32, 16), 256, 0, stream>>>(ctxh, wt + 3 * P, bo, out);
}

// Round 9
// 166.818 us; speedup vs baseline: 1.9108x; 1.0242x over previous
//
#include <hip/hip_runtime.h>
#include <hip/hip_bf16.h>
#include <cstdint>

typedef __attribute__((ext_vector_type(8))) short short8;
typedef __attribute__((ext_vector_type(4))) float f32x4;
typedef __attribute__((ext_vector_type(4))) float float4v;
typedef __attribute__((ext_vector_type(4))) unsigned short us4;

#define HD 1024
#define SEQ 2048

// fp32 -> bf16 (round-to-nearest-even), raw bits; inputs are finite.
__device__ __forceinline__ unsigned short f2bf(float f) {
  uint32_t u = __builtin_bit_cast(uint32_t, f);
  return (unsigned short)((u + 0x7FFFu + ((u >> 16) & 1u)) >> 16);
}
__device__ __forceinline__ float bf2f(unsigned short s) {
  return __builtin_bit_cast(float, (uint32_t)s << 16);
}

// async global->LDS, 16B per lane, dest = wave-uniform base + lane*16
__device__ __forceinline__ void gload16(const unsigned short* g, unsigned short* l) {
  __builtin_amdgcn_global_load_lds(
      (const __attribute__((address_space(1))) void*)g,
      (__attribute__((address_space(3))) void*)l, 16, 0, 0);
}

// ---------------- fused prep ----------------
// bx [0,4096):    bf16 cast of inputs (bx<2048) / context
// bx [4096,8192): transpose + bf16 cast of weight (bx-4096)>>10
__global__ __launch_bounds__(256) void prep(
    const float* __restrict__ X, const float* __restrict__ Y,
    const float* __restrict__ w0, const float* __restrict__ w1,
    const float* __restrict__ w2, const float* __restrict__ w3,
    unsigned short* __restrict__ Xh, unsigned short* __restrict__ Yh,
    unsigned short* __restrict__ wt) {
  __shared__ float tile[32][33];
  int bx = blockIdx.x;
  int tid = threadIdx.x;
  if (bx < 4096) {
    const float* src = (bx >= 2048) ? Y : X;
    unsigned short* oh = (bx >= 2048) ? Yh : Xh;
    int i0 = (bx & 2047) * 512 + tid;
#pragma unroll
    for (int r = 0; r < 2; ++r) {
      int i = i0 + r * 256;
      float4v v = ((const float4v*)src)[i];
      us4 h;
#pragma unroll
      for (int j = 0; j < 4; ++j) h[j] = f2bf(v[j]);
      ((us4*)oh)[i] = h;
    }
  } else {
    int t = bx - 4096;
    int z = t >> 10;
    int rem = t & 1023;
    int bxx = rem & 31, byy = rem >> 5;
    const float* in = (z == 0) ? w0 : (z == 1) ? w1 : (z == 2) ? w2 : w3;
    unsigned short* oh = wt + (size_t)z * 1024 * 1024;
    int tx = tid & 31, ty = tid >> 5;
    int x = bxx * 32 + tx;
    int y0 = byy * 32;
    for (int i = ty; i < 32; i += 8)
      tile[i][tx] = in[(size_t)(y0 + i) * HD + x];
    __syncthreads();
    int x2 = y0 + tx;               // k index after transpose
    int y2 = bxx * 32;              // n index after transpose
    for (int i = ty; i < 32; i += 8)
      oh[(size_t)(y2 + i) * HD + x2] = f2bf(tile[tx][i]);
  }
}

// ---------------- batched QKV GEMM, pure bf16, BK=64 ----------------
// z=0: q = inputs@Wq+bq ; z=1: k = context@Wk+bk ; z=2: v = context@Wv+bv.
// 128x128 tile, 256 thr = 4 waves (2m x 2n), wave tile 64x64.
// LDS: 2 planes [128][64], XOR-swizzled 8-chunk rows (slot c of row r holds
// global chunk c ^ ((r>>1)&7)); seg parity folds into two per-lane src ptrs.
__global__ __launch_bounds__(256, 3) void gemm_qkv(
    const unsigned short* __restrict__ Ih, const unsigned short* __restrict__ Ch,
    const unsigned short* __restrict__ wt,
    const float* __restrict__ bq, const float* __restrict__ bk, const float* __restrict__ bv,
    unsigned short* __restrict__ qo, unsigned short* __restrict__ ko,
    unsigned short* __restrict__ vo) {
  __shared__ __align__(16) unsigned short lds[2][128][64];
  const int K = HD, N = HD;
  const size_t P = (size_t)1024 * 1024;
  int z  = blockIdx.z;
  const unsigned short* Ah = z ? Ch : Ih;
  const unsigned short* Bth = wt + (size_t)z * P;
  const float* bias = (z == 0) ? bq : (z == 1) ? bk : bv;
  unsigned short* C = (z == 0) ? qo : (z == 1) ? ko : vo;

  int m0 = blockIdx.x * 128;
  int n0 = blockIdx.y * 128;
  int tid  = threadIdx.x;
  int lane = tid & 63;
  int w    = tid >> 6;            // 0..3
  int quad = lane >> 4;
  int l16  = lane & 15;
  int wm = (w >> 1) * 64;
  int wn = (w & 1) * 64;

  int ro = lane >> 3;             // 0..7 row-in-seg
  int sl = lane & 7;              // slot
  int ge = sl ^ (ro >> 1);        // even-seg global chunk
  int go = ge ^ 4;                // odd-seg
  const unsigned short* spA_e = Ah  + (size_t)(m0 + ro) * K + ge * 8;
  const unsigned short* spA_o = Ah  + (size_t)(m0 + ro) * K + go * 8;
  const unsigned short* spB_e = Bth + (size_t)(n0 + ro) * K + ge * 8;
  const unsigned short* spB_o = Bth + (size_t)(n0 + ro) * K + go * 8;

  f32x4 acc[4][4];
#pragma unroll
  for (int t = 0; t < 4; ++t)
#pragma unroll
    for (int u = 0; u < 4; ++u) acc[t][u] = (f32x4){0.f, 0.f, 0.f, 0.f};

  for (int k0 = 0; k0 < K; k0 += 64) {
    __syncthreads();
#pragma unroll
    for (int i = 0; i < 4; ++i) {
      int seg = w + i * 4;
      const unsigned short* pa = (seg & 1) ? spA_o : spA_e;
      const unsigned short* pb = (seg & 1) ? spB_o : spB_e;
      gload16(pa + (size_t)seg * 8 * K + k0, &lds[0][seg * 8][0]);
      gload16(pb + (size_t)seg * 8 * K + k0, &lds[1][seg * 8][0]);
    }
    __syncthreads();

#pragma unroll
    for (int j = 0; j < 2; ++j) {
      int sl8 = (((j << 2) | quad) ^ (l16 >> 1)) * 8;
      short8 ah[4], bh[4];
#pragma unroll
      for (int t = 0; t < 4; ++t)
        ah[t] = *(const short8*)&lds[0][wm + t * 16 + l16][sl8];
#pragma unroll
      for (int u = 0; u < 4; ++u)
        bh[u] = *(const short8*)&lds[1][wn + u * 16 + l16][sl8];
#pragma unroll
      for (int t = 0; t < 4; ++t)
#pragma unroll
        for (int u = 0; u < 4; ++u)
          acc[t][u] = __builtin_amdgcn_mfma_f32_16x16x32_bf16(ah[t], bh[u], acc[t][u], 0, 0, 0);
    }
  }

#pragma unroll
  for (int t = 0; t < 4; ++t) {
    int row = m0 + wm + t * 16 + quad * 4;
#pragma unroll
    for (int u = 0; u < 4; ++u) {
      int col = n0 + wn + u * 16 + l16;
      float bvv = bias[col];
#pragma unroll
      for (int i = 0; i < 4; ++i)
        C[(size_t)(row + i) * N + col] = f2bf(acc[t][u][i] + bvv);
    }
  }
}

// ---------------- O GEMM, pure bf16, 128x64 tile, direct write ----------------
// grid (32,16) = 512 blocks (2/CU). Full K per block -> no atomics, no zero-fill.
// 4 waves (2m x 2n), wave tile 64x32 (4x2 accs). LDS A[128][64] + B[64][64].
__global__ __launch_bounds__(256, 3) void gemm_o(
    const unsigned short* __restrict__ Ah, const unsigned short* __restrict__ Bth,
    const float* __restrict__ bias, float* __restrict__ C) {
  __shared__ __align__(16) unsigned short ldsA[128][64];
  __shared__ __align__(16) unsigned short ldsB[64][64];
  const int K = HD, N = HD;
  int m0 = blockIdx.x * 128;
  int n0 = blockIdx.y * 64;
  int tid  = threadIdx.x;
  int lane = tid & 63;
  int w    = tid >> 6;            // 0..3
  int quad = lane >> 4;
  int l16  = lane & 15;
  int wm = (w >> 1) * 64;         // 0/64
  int wn = (w & 1) * 32;          // 0/32

  int ro = lane >> 3;
  int sl = lane & 7;
  int ge = sl ^ (ro >> 1);
  int go = ge ^ 4;
  const unsigned short* spA_e = Ah  + (size_t)(m0 + ro) * K + ge * 8;
  const unsigned short* spA_o = Ah  + (size_t)(m0 + ro) * K + go * 8;
  const unsigned short* spB_e = Bth + (size_t)(n0 + ro) * K + ge * 8;
  const unsigned short* spB_o = Bth + (size_t)(n0 + ro) * K + go * 8;

  f32x4 acc[4][2];
#pragma unroll
  for (int t = 0; t < 4; ++t)
#pragma unroll
    for (int u = 0; u < 2; ++u) acc[t][u] = (f32x4){0.f, 0.f, 0.f, 0.f};

  for (int k0 = 0; k0 < K; k0 += 64) {
    __syncthreads();
#pragma unroll
    for (int i = 0; i < 4; ++i) {          // A segs: w, w+4, w+8, w+12
      int seg = w + i * 4;
      const unsigned short* pa = (seg & 1) ? spA_o : spA_e;
      gload16(pa + (size_t)seg * 8 * K + k0, &ldsA[seg * 8][0]);
    }
#pragma unroll
    for (int i = 0; i < 2; ++i) {          // B segs: w, w+4
      int seg = w + i * 4;
      const unsigned short* pb = (seg & 1) ? spB_o : spB_e;
      gload16(pb + (size_t)seg * 8 * K + k0, &ldsB[seg * 8][0]);
    }
    __syncthreads();

#pragma unroll
    for (int j = 0; j < 2; ++j) {
      int sl8 = (((j << 2) | quad) ^ (l16 >> 1)) * 8;
      short8 ah[4], bh[2];
#pragma unroll
      for (int t = 0; t < 4; ++t)
        ah[t] = *(const short8*)&ldsA[wm + t * 16 + l16][sl8];
#pragma unroll
      for (int u = 0; u < 2; ++u)
        bh[u] = *(const short8*)&ldsB[wn + u * 16 + l16][sl8];
#pragma unroll
      for (int t = 0; t < 4; ++t)
#pragma unroll
        for (int u = 0; u < 2; ++u)
          acc[t][u] = __builtin_amdgcn_mfma_f32_16x16x32_bf16(ah[t], bh[u], acc[t][u], 0, 0, 0);
    }
  }

#pragma unroll
  for (int t = 0; t < 4; ++t) {
    int row = m0 + wm + t * 16 + quad * 4;
#pragma unroll
    for (int u = 0; u < 2; ++u) {
      int col = n0 + wn + u * 16 + l16;
      float bvv = bias[col];
#pragma unroll
      for (int i = 0; i < 4; ++i)
        C[(size_t)(row + i) * N + col] = acc[t][u][i] + bvv;
    }
  }
}

// ---------------- fused RoPE + per-(b,s) head-attention ----------------
// bf16 q/k/v in, fp32 compute; RoPE trig via hardware v_sin/v_cos (fract-reduced
// revolutions, error ~4e-4 rad -- well inside the bf16 error budget);
// attn fp32 out; ctx bf16 out in the transpose(0,2,1,3) scrambled layout.
__global__ __launch_bounds__(256) void attn_rope_k(
    const unsigned short* __restrict__ q, const unsigned short* __restrict__ kk,
    const unsigned short* __restrict__ v,
    float* __restrict__ attn_out, unsigned short* __restrict__ ctx_h) {
  __shared__ float qs[16][68], ks[16][68], vs[16][68], as[16][17];
  int m = blockIdx.x;            // b*S + s
  int tid = threadIdx.x;
  int s = m & (SEQ - 1);
  size_t base4 = (size_t)m * (HD / 4);
  {
    int h = tid >> 4, dd = (tid & 15) * 4;
    us4 qv = ((const us4*)q)[base4 + tid];
    us4 kv = ((const us4*)kk)[base4 + tid];
    us4 vv = ((const us4*)v)[base4 + tid];
#pragma unroll
    for (int j = 0; j < 4; ++j) {
      qs[h][dd + j] = bf2f(qv[j]);
      ks[h][dd + j] = bf2f(kv[j]);
      vs[h][dd + j] = bf2f(vv[j]);
    }
  }
  __syncthreads();
  // RoPE: pairs (d, d+512) over flat hidden -> (h, dd) with (h+8, dd)
#pragma unroll
  for (int d = tid; d < 512; d += 256) {
    // theta = s * 10000^(-d/512); rev = theta/(2*pi); hw sin/cos on fract(rev)
    float f = exp2f(-(float)d * 0.025952563241307517f);  // log2(10000)/512
    float rev = (float)s * (f * 0.15915494309189535f);
    rev -= floorf(rev);
    float sv = __builtin_amdgcn_sinf(rev);
    float cv = __builtin_amdgcn_cosf(rev);
    int h1 = d >> 6, dd = d & 63, h2 = h1 + 8;
    float q1 = qs[h1][dd], q2 = qs[h2][dd];
    qs[h1][dd] = q1 * cv - q2 * sv;
    qs[h2][dd] = q2 * cv + q1 * sv;
    float k1 = ks[h1][dd], k2 = ks[h2][dd];
    ks[h1][dd] = k1 * cv - k2 * sv;
    ks[h2][dd] = k2 * cv + k1 * sv;
  }
  __syncthreads();
  int h = tid >> 4, t = tid & 15;
  float sc = 0.f;
#pragma unroll
  for (int d = 0; d < 64; ++d) sc = fmaf(qs[h][d], ks[t][d], sc);
  sc *= 0.125f;   // 1/sqrt(64)
  float mx = sc;
  mx = fmaxf(mx, __shfl_xor(mx, 1));
  mx = fmaxf(mx, __shfl_xor(mx, 2));
  mx = fmaxf(mx, __shfl_xor(mx, 4));
  mx = fmaxf(mx, __shfl_xor(mx, 8));
  float e = expf(sc - mx);
  float sum = e;
  sum += __shfl_xor(sum, 1);
  sum += __shfl_xor(sum, 2);
  sum += __shfl_xor(sum, 4);
  sum += __shfl_xor(sum, 8);
  float a = e / sum;
  attn_out[(size_t)m * 256 + tid] = a;
  as[h][t] = a;
  __syncthreads();
  int b = m >> 11;
  for (int j = tid; j < 1024; j += 256) {
    int h2 = j >> 6, d = j & 63;
    float c = 0.f;
#pragma unroll
    for (int t2 = 0; t2 < 16; ++t2) c = fmaf(as[h2][t2], vs[t2][d], c);
    int row = b * SEQ + h2 * 128 + (s >> 4);
    int col = (s & 15) * 64 + d;
    ctx_h[(size_t)row * HD + col] = f2bf(c);
  }
}

extern "C" void kernel_launch(void* const* d_in, const int* in_sizes, int n_in,
                              void* d_out, int out_size, void* d_ws, size_t ws_size,
                              hipStream_t stream) {
  const float* inputs  = (const float*)d_in[0];
  const float* context = (const float*)d_in[1];
  const float* Wq = (const float*)d_in[2];
  const float* bq = (const float*)d_in[3];
  const float* Wk = (const float*)d_in[4];
  const float* bk = (const float*)d_in[5];
  const float* Wv = (const float*)d_in[6];
  const float* bv = (const float*)d_in[7];
  const float* Wo = (const float*)d_in[8];
  const float* bo = (const float*)d_in[9];

  float* out  = (float*)d_out;                     // [2,2048,1024] flat
  float* attn = out + (size_t)4096 * 1024;         // [2,2048,16,16] flat

  // ws layout (MB offsets): q=0, k=8, v=16, wt=24..32, Ih=32..40, Ch=40..48.
  // ctxh aliases Ih (dead after gemm_qkv; cross-dispatch only).
  const size_t MB = 1ull << 20;
  char* wsb = (char*)d_ws;
  unsigned short* q  = (unsigned short*)(wsb + 0 * MB);
  unsigned short* k  = (unsigned short*)(wsb + 8 * MB);
  unsigned short* v  = (unsigned short*)(wsb + 16 * MB);
  unsigned short* wt = (unsigned short*)(wsb + 24 * MB);
  unsigned short* Ih = (unsigned short*)(wsb + 32 * MB);
  unsigned short* Ch = (unsigned short*)(wsb + 40 * MB);
  unsigned short* ctxh = Ih;   // alias, cross-dispatch only

  prep<<<8192, 256, 0, stream>>>(inputs, context, Wq, Wk, Wv, Wo, Ih, Ch, wt);

  gemm_qkv<<<dim3(32, 8, 3), 256, 0, stream>>>(Ih, Ch, wt, bq, bk, bv, q, k, v);

  attn_rope_k<<<4096, 256, 0, stream>>>(q, k, v, attn, ctxh);

  const size_t P = (size_t)1024 * 1024;
  gemm_o<<<dim3(32, 16), 256, 0, stream>>>(ctxh, wt + 3 * P, bo, out);
}